// Round 3
// baseline (818.288 us; speedup 1.0000x reference)
//
#include <hip/hip_runtime.h>
#include <hip/hip_bf16.h>

#define N_NODES 100000
#define N_EDGES 3200000
#define IN_CH 128
#define HID 16
#define OUT_CH 64
#define BSHIFT 7
#define BNODES 128              // nodes per bucket
#define NBUCK 782               // ceil(100000/128)

// ---------------- pass 0: global bucket histogram (LDS-privatized) ----------------
__global__ __launch_bounds__(256) void k_hist0(const int* __restrict__ dst, int* __restrict__ hist, int e) {
    __shared__ int lh[NBUCK];
    int t = threadIdx.x;
    for (int i = t; i < NBUCK; i += 256) lh[i] = 0;
    __syncthreads();
    int base = blockIdx.x * 8192;
    for (int j = 0; j < 32; ++j) {
        int idx = base + j * 256 + t;
        if (idx < e) atomicAdd(&lh[dst[idx] >> BSHIFT], 1);
    }
    __syncthreads();
    for (int i = t; i < NBUCK; i += 256) if (lh[i]) atomicAdd(&hist[i], lh[i]);
}

// ---------------- scan 782 bucket counts -> base + cursor ----------------
__global__ __launch_bounds__(1024) void k_scan0(const int* __restrict__ hist, int* __restrict__ bse,
                                                int* __restrict__ cur) {
    __shared__ int sh[1024];
    int t = threadIdx.x;
    int v = (t < NBUCK) ? hist[t] : 0;
    sh[t] = v;
    __syncthreads();
    for (int off = 1; off < 1024; off <<= 1) {
        int x = (t >= off) ? sh[t - off] : 0;
        __syncthreads();
        sh[t] += x;
        __syncthreads();
    }
    if (t < NBUCK) { int ex = sh[t] - v; bse[t] = ex; cur[t] = ex; }
}

// ---------------- pass 1: scatter packed edges into buckets (block-coalesced runs) ----------------
__global__ __launch_bounds__(256) void k_bucket(const int* __restrict__ src, const int* __restrict__ dst,
                                                int* __restrict__ cur, unsigned* __restrict__ colp, int e) {
    __shared__ int lh[NBUCK];
    __shared__ int lb[NBUCK];
    int t = threadIdx.x;
    for (int i = t; i < NBUCK; i += 256) lh[i] = 0;
    __syncthreads();
    int base = blockIdx.x * 2048;
    int bk[8]; int rk[8]; unsigned pk[8];
#pragma unroll
    for (int j = 0; j < 8; ++j) {
        int idx = base + j * 256 + t;
        if (idx < e) {
            int d = dst[idx];
            int b = d >> BSHIFT;
            bk[j] = b;
            pk[j] = ((unsigned)(d & (BNODES - 1)) << 17) | (unsigned)src[idx];
            rk[j] = atomicAdd(&lh[b], 1);
        } else bk[j] = -1;
    }
    __syncthreads();
    for (int i = t; i < NBUCK; i += 256) { int c = lh[i]; lb[i] = c ? atomicAdd(&cur[i], c) : 0; }
    __syncthreads();
#pragma unroll
    for (int j = 0; j < 8; ++j) if (bk[j] >= 0) colp[lb[bk[j]] + rk[j]] = pk[j];
}

// ---------------- per-bucket degree -> dinv ----------------
__global__ __launch_bounds__(256) void k_deg(const unsigned* __restrict__ colp, const int* __restrict__ bse,
                                             const int* __restrict__ hist, float* __restrict__ dinv) {
    __shared__ int ld[BNODES];
    int b = blockIdx.x, t = threadIdx.x;
    if (t < BNODES) ld[t] = 0;
    __syncthreads();
    int base = bse[b], cnt = hist[b];
    for (int i = t; i < cnt; i += 256) atomicAdd(&ld[colp[base + i] >> 17], 1);
    __syncthreads();
    int node = b * BNODES + t;
    if (t < BNODES && node < N_NODES) dinv[node] = rsqrtf((float)ld[t] + 1.0f);
}

// ---------------- h1 = x @ W1  (N x 128) @ (128 x 16) ----------------
__global__ __launch_bounds__(256) void k_gemm1(const float* __restrict__ x,
                                               const float* __restrict__ W1,
                                               float* __restrict__ h1, int n) {
    __shared__ float Ws[IN_CH * HID];
    __shared__ float xs[16][IN_CH + 1];
    int tid = threadIdx.x;
    for (int i = tid; i < IN_CH * HID; i += 256) Ws[i] = W1[i];
    int row0 = blockIdx.x * 16;
    for (int i = tid; i < 16 * IN_CH; i += 256) {
        int r = i / IN_CH, c = i % IN_CH;
        int row = row0 + r;
        xs[r][c] = (row < n) ? x[(size_t)row * IN_CH + c] : 0.f;
    }
    __syncthreads();
    int r = tid >> 4, c = tid & 15;
    float acc = 0.f;
#pragma unroll
    for (int k = 0; k < IN_CH; ++k) acc = fmaf(xs[r][k], Ws[k * HID + c], acc);
    int row = row0 + r;
    if (row < n) h1[(size_t)row * HID + c] = acc;
}

// ---------------- layer-1 aggregation in LDS + bias + relu ----------------
__global__ __launch_bounds__(256) void k_gather1(const unsigned* __restrict__ colp, const int* __restrict__ bse,
                                                 const int* __restrict__ hist, const float* __restrict__ dinv,
                                                 const float* __restrict__ h1, const float* __restrict__ b1,
                                                 float* __restrict__ h2) {
    __shared__ float acc[BNODES][HID + 1];
    __shared__ float dl[BNODES];
    int b = blockIdx.x, t = threadIdx.x;
    for (int i = t; i < BNODES * (HID + 1); i += 256) ((float*)acc)[i] = 0.f;
    if (t < BNODES) { int node = b * BNODES + t; dl[t] = (node < N_NODES) ? dinv[node] : 0.f; }
    __syncthreads();
    int base = bse[b];
    int m = hist[b] * 4;
    int q = t & 3;
    for (int i = t; i < m; i += 256) {
        unsigned v = colp[base + (i >> 2)];
        int s = v & 0x1FFFF;
        int l = v >> 17;
        float w = dinv[s] * dl[l];
        float4 hv = *reinterpret_cast<const float4*>(&h1[(size_t)s * HID + q * 4]);
        atomicAdd(&acc[l][q * 4 + 0], hv.x * w);
        atomicAdd(&acc[l][q * 4 + 1], hv.y * w);
        atomicAdd(&acc[l][q * 4 + 2], hv.z * w);
        atomicAdd(&acc[l][q * 4 + 3], hv.w * w);
    }
    __syncthreads();
    int l = t >> 1, c0 = (t & 1) * 8;
    int node = b * BNODES + l;
    if (node < N_NODES) {
        float dii = dl[l] * dl[l];
        float4 s0 = *reinterpret_cast<const float4*>(&h1[(size_t)node * HID + c0]);
        float4 s1 = *reinterpret_cast<const float4*>(&h1[(size_t)node * HID + c0 + 4]);
        float4 o0, o1;
        o0.x = fmaxf(acc[l][c0 + 0] + dii * s0.x + b1[c0 + 0], 0.f);
        o0.y = fmaxf(acc[l][c0 + 1] + dii * s0.y + b1[c0 + 1], 0.f);
        o0.z = fmaxf(acc[l][c0 + 2] + dii * s0.z + b1[c0 + 2], 0.f);
        o0.w = fmaxf(acc[l][c0 + 3] + dii * s0.w + b1[c0 + 3], 0.f);
        o1.x = fmaxf(acc[l][c0 + 4] + dii * s1.x + b1[c0 + 4], 0.f);
        o1.y = fmaxf(acc[l][c0 + 5] + dii * s1.y + b1[c0 + 5], 0.f);
        o1.z = fmaxf(acc[l][c0 + 6] + dii * s1.z + b1[c0 + 6], 0.f);
        o1.w = fmaxf(acc[l][c0 + 7] + dii * s1.w + b1[c0 + 7], 0.f);
        *reinterpret_cast<float4*>(&h2[(size_t)node * HID + c0]) = o0;
        *reinterpret_cast<float4*>(&h2[(size_t)node * HID + c0 + 4]) = o1;
    }
}

// ---------------- layer-2 aggregation in LDS + fused 16x64 GEMM + bias ----------------
__global__ __launch_bounds__(256) void k_gather2(const unsigned* __restrict__ colp, const int* __restrict__ bse,
                                                 const int* __restrict__ hist, const float* __restrict__ dinv,
                                                 const float* __restrict__ h2, const float* __restrict__ W2,
                                                 const float* __restrict__ b2, float* __restrict__ out) {
    __shared__ float acc[BNODES][HID + 1];
    __shared__ float dl[BNODES];
    __shared__ float Ws[HID * OUT_CH];
    int b = blockIdx.x, t = threadIdx.x;
    for (int i = t; i < BNODES * (HID + 1); i += 256) ((float*)acc)[i] = 0.f;
    for (int i = t; i < HID * OUT_CH; i += 256) Ws[i] = W2[i];
    if (t < BNODES) { int node = b * BNODES + t; dl[t] = (node < N_NODES) ? dinv[node] : 0.f; }
    __syncthreads();
    int base = bse[b];
    int m = hist[b] * 4;
    int q = t & 3;
    for (int i = t; i < m; i += 256) {
        unsigned v = colp[base + (i >> 2)];
        int s = v & 0x1FFFF;
        int l = v >> 17;
        float w = dinv[s] * dl[l];
        float4 hv = *reinterpret_cast<const float4*>(&h2[(size_t)s * HID + q * 4]);
        atomicAdd(&acc[l][q * 4 + 0], hv.x * w);
        atomicAdd(&acc[l][q * 4 + 1], hv.y * w);
        atomicAdd(&acc[l][q * 4 + 2], hv.z * w);
        atomicAdd(&acc[l][q * 4 + 3], hv.w * w);
    }
    __syncthreads();
    {   // self-loop contribution into LDS accumulator
        int l = t >> 1, c0 = (t & 1) * 8;
        int node = b * BNODES + l;
        if (node < N_NODES) {
            float dii = dl[l] * dl[l];
#pragma unroll
            for (int c = 0; c < 8; ++c) acc[l][c0 + c] += dii * h2[(size_t)node * HID + c0 + c];
        }
    }
    __syncthreads();
    int l = t >> 1, g = t & 1;
    int node = b * BNODES + l;
    if (node < N_NODES) {
        float r[32];
#pragma unroll
        for (int c = 0; c < 32; ++c) r[c] = b2[g * 32 + c];
#pragma unroll
        for (int k = 0; k < HID; ++k) {
            float a = acc[l][k];
#pragma unroll
            for (int c = 0; c < 32; ++c) r[c] = fmaf(a, Ws[k * OUT_CH + g * 32 + c], r[c]);
        }
        float* op = &out[(size_t)node * OUT_CH + g * 32];
#pragma unroll
        for (int c = 0; c < 32; c += 4)
            *reinterpret_cast<float4*>(&op[c]) = make_float4(r[c], r[c + 1], r[c + 2], r[c + 3]);
    }
}

extern "C" void kernel_launch(void* const* d_in, const int* in_sizes, int n_in,
                              void* d_out, int out_size, void* d_ws, size_t ws_size,
                              hipStream_t stream) {
    const float* x  = (const float*)d_in[0];
    const int*   ei = (const int*)d_in[1];
    const float* W1 = (const float*)d_in[2];
    const float* b1 = (const float*)d_in[3];
    const float* W2 = (const float*)d_in[4];
    const float* b2 = (const float*)d_in[5];
    float* out = (float*)d_out;

    const int* src = ei;
    const int* dst = ei + N_EDGES;

    // workspace layout (4B units)
    int*      hist = (int*)d_ws;                    // [0, 800)
    int*      bse  = hist + 800;                    // [800, 1600)
    int*      cur  = bse + 800;                     // [1600, 2400)
    float*    dinv = (float*)(cur + 800);           // [2400, 102400)
    unsigned* colp = (unsigned*)(dinv + 100000);    // [102400, 3302400)
    float*    h1   = (float*)(colp + N_EDGES);      // [3302400, 4902400)
    float*    h2   = h1 + (size_t)N_NODES * HID;    // [4902400, 6502400)  ~26 MB total

    hipMemsetAsync(hist, 0, NBUCK * sizeof(int), stream);
    k_hist0<<<(N_EDGES + 8191) / 8192, 256, 0, stream>>>(dst, hist, N_EDGES);
    k_scan0<<<1, 1024, 0, stream>>>(hist, bse, cur);
    k_bucket<<<(N_EDGES + 2047) / 2048, 256, 0, stream>>>(src, dst, cur, colp, N_EDGES);
    k_deg<<<NBUCK, 256, 0, stream>>>(colp, bse, hist, dinv);

    k_gemm1<<<(N_NODES + 15) / 16, 256, 0, stream>>>(x, W1, h1, N_NODES);

    k_gather1<<<NBUCK, 256, 0, stream>>>(colp, bse, hist, dinv, h1, b1, h2);
    k_gather2<<<NBUCK, 256, 0, stream>>>(colp, bse, hist, dinv, h2, W2, b2, out);
}

// Round 4
// 273.163 us; speedup vs baseline: 2.9956x; 2.9956x over previous
//
#include <hip/hip_runtime.h>
#include <hip/hip_bf16.h>

#define N_NODES 100000
#define N_EDGES 3200000
#define IN_CH 128
#define HID 16
#define OUT_CH 64
#define BSHIFT 7
#define BNODES 128              // nodes per bucket
#define NBUCK 782               // ceil(100000/128)

// ---------------- pass 0: global bucket histogram (LDS-privatized) ----------------
__global__ __launch_bounds__(256) void k_hist0(const int* __restrict__ dst, int* __restrict__ hist, int e) {
    __shared__ int lh[NBUCK];
    int t = threadIdx.x;
    for (int i = t; i < NBUCK; i += 256) lh[i] = 0;
    __syncthreads();
    int base = blockIdx.x * 8192;
    for (int j = 0; j < 32; ++j) {
        int idx = base + j * 256 + t;
        if (idx < e) atomicAdd(&lh[dst[idx] >> BSHIFT], 1);
    }
    __syncthreads();
    for (int i = t; i < NBUCK; i += 256) if (lh[i]) atomicAdd(&hist[i], lh[i]);
}

// ---------------- scan 782 bucket counts -> base + cursor ----------------
__global__ __launch_bounds__(1024) void k_scan0(const int* __restrict__ hist, int* __restrict__ bse,
                                                int* __restrict__ cur) {
    __shared__ int sh[1024];
    int t = threadIdx.x;
    int v = (t < NBUCK) ? hist[t] : 0;
    sh[t] = v;
    __syncthreads();
    for (int off = 1; off < 1024; off <<= 1) {
        int x = (t >= off) ? sh[t - off] : 0;
        __syncthreads();
        sh[t] += x;
        __syncthreads();
    }
    if (t < NBUCK) { int ex = sh[t] - v; bse[t] = ex; cur[t] = ex; }
}

// ---------------- pass 1: scatter packed edges into bucket runs (block-coalesced) ----------------
__global__ __launch_bounds__(256) void k_bucket(const int* __restrict__ src, const int* __restrict__ dst,
                                                int* __restrict__ cur, unsigned* __restrict__ colp, int e) {
    __shared__ int lh[NBUCK];
    __shared__ int lb[NBUCK];
    int t = threadIdx.x;
    for (int i = t; i < NBUCK; i += 256) lh[i] = 0;
    __syncthreads();
    int base = blockIdx.x * 2048;
    int bk[8]; int rk[8]; unsigned pk[8];
#pragma unroll
    for (int j = 0; j < 8; ++j) {
        int idx = base + j * 256 + t;
        if (idx < e) {
            int d = dst[idx];
            int b = d >> BSHIFT;
            bk[j] = b;
            pk[j] = ((unsigned)(d & (BNODES - 1)) << 17) | (unsigned)src[idx];
            rk[j] = atomicAdd(&lh[b], 1);
        } else bk[j] = -1;
    }
    __syncthreads();
    for (int i = t; i < NBUCK; i += 256) { int c = lh[i]; lb[i] = c ? atomicAdd(&cur[i], c) : 0; }
    __syncthreads();
#pragma unroll
    for (int j = 0; j < 8; ++j) if (bk[j] >= 0) colp[lb[bk[j]] + rk[j]] = pk[j];
}

// ---------------- pass 2: per-bucket counting sort -> CSR (col, row_ptr, deg, dinv) ----------------
// One block per bucket. All scatter writes land in the bucket's ~16KB run while it is
// resident in one XCD's L2, so 4B stores merge into full lines (no 64B amplification).
__global__ __launch_bounds__(256) void k_build(const unsigned* __restrict__ colp, const int* __restrict__ bse,
                                               const int* __restrict__ hist, int* __restrict__ col,
                                               int* __restrict__ row_ptr, int* __restrict__ deg,
                                               float* __restrict__ dinv) {
    __shared__ int cnt[BNODES];
    __shared__ int sc[BNODES];
    __shared__ int ex[BNODES];
    __shared__ int curl[BNODES];
    int b = blockIdx.x, t = threadIdx.x;
    if (t < BNODES) cnt[t] = 0;
    __syncthreads();
    int base = bse[b], m = hist[b];
    for (int i = t; i < m; i += 256) atomicAdd(&cnt[colp[base + i] >> 17], 1);
    __syncthreads();
    if (t < BNODES) sc[t] = cnt[t];
    __syncthreads();
    for (int off = 1; off < BNODES; off <<= 1) {
        int x = 0;
        if (t < BNODES && t >= off) x = sc[t - off];
        __syncthreads();
        if (t < BNODES) sc[t] += x;
        __syncthreads();
    }
    if (t < BNODES) {
        ex[t] = sc[t] - cnt[t];
        curl[t] = 0;
        int node = b * BNODES + t;
        if (node < N_NODES) {
            row_ptr[node] = base + ex[t];
            deg[node] = cnt[t];
            dinv[node] = rsqrtf((float)cnt[t] + 1.0f);
        }
    }
    __syncthreads();
    for (int i = t; i < m; i += 256) {
        unsigned v = colp[base + i];
        int l = v >> 17;
        int p = atomicAdd(&curl[l], 1);
        col[base + ex[l] + p] = (int)(v & 0x1FFFF);
    }
}

// ---------------- h1' = dinv * (x @ W1)  (N x 128) @ (128 x 16) ----------------
__global__ __launch_bounds__(256) void k_gemm1(const float* __restrict__ x,
                                               const float* __restrict__ W1,
                                               const float* __restrict__ dinv,
                                               float* __restrict__ h1p, int n) {
    __shared__ float Ws[IN_CH * HID];
    __shared__ float xs[16][IN_CH + 1];
    int tid = threadIdx.x;
    for (int i = tid; i < IN_CH * HID; i += 256) Ws[i] = W1[i];
    int row0 = blockIdx.x * 16;
    for (int i = tid; i < 16 * IN_CH; i += 256) {
        int r = i / IN_CH, c = i % IN_CH;
        int row = row0 + r;
        xs[r][c] = (row < n) ? x[(size_t)row * IN_CH + c] : 0.f;
    }
    __syncthreads();
    int r = tid >> 4, c = tid & 15;
    float acc = 0.f;
#pragma unroll
    for (int k = 0; k < IN_CH; ++k) acc = fmaf(xs[r][k], Ws[k * HID + c], acc);
    int row = row0 + r;
    if (row < n) h1p[(size_t)row * HID + c] = dinv[row] * acc;
}

// ---------------- gather layer 1: h2' = dinv * relu(dinv*(h1p[i] + sum h1p[col]) + b1) ----------------
__global__ void k_gather1(const float* __restrict__ h1p, const int* __restrict__ row_ptr,
                          const int* __restrict__ deg, const float* __restrict__ dinv,
                          const int* __restrict__ col, const float* __restrict__ b1,
                          float* __restrict__ h2p, int n) {
    int t = blockIdx.x * blockDim.x + threadIdx.x;
    int i = t >> 2, q = t & 3;
    if (i >= n) return;
    float4 acc = *reinterpret_cast<const float4*>(&h1p[(size_t)i * HID + q * 4]);  // self-loop
    int j0 = row_ptr[i], j1 = j0 + deg[i];
    for (int j = j0; j < j1; ++j) {
        int s = col[j];
        float4 v = *reinterpret_cast<const float4*>(&h1p[(size_t)s * HID + q * 4]);
        acc.x += v.x; acc.y += v.y; acc.z += v.z; acc.w += v.w;
    }
    float di = dinv[i];
    float4 b = *reinterpret_cast<const float4*>(&b1[q * 4]);
    float4 o;
    o.x = di * fmaxf(fmaf(di, acc.x, b.x), 0.f);
    o.y = di * fmaxf(fmaf(di, acc.y, b.y), 0.f);
    o.z = di * fmaxf(fmaf(di, acc.z, b.z), 0.f);
    o.w = di * fmaxf(fmaf(di, acc.w, b.w), 0.f);
    *reinterpret_cast<float4*>(&h2p[(size_t)i * HID + q * 4]) = o;
}

// ---------------- gather layer 2 fused with (N x 16)@(16 x 64) + b2 ----------------
__global__ __launch_bounds__(256) void k_gather2_out(const float* __restrict__ h2p,
                                                     const int* __restrict__ row_ptr,
                                                     const int* __restrict__ deg,
                                                     const float* __restrict__ dinv,
                                                     const int* __restrict__ col,
                                                     const float* __restrict__ W2,
                                                     const float* __restrict__ b2,
                                                     float* __restrict__ out, int n) {
    __shared__ float Ws[HID * OUT_CH];   // 1024 f
    __shared__ float as[64][HID + 1];    // padded
    int t = threadIdx.x;
    for (int i = t; i < HID * OUT_CH; i += 256) Ws[i] = W2[i];
    int i0 = blockIdx.x * 64;
    int nl = t >> 2, q = t & 3;
    int i = i0 + nl;
    if (i < n) {
        float4 acc = *reinterpret_cast<const float4*>(&h2p[(size_t)i * HID + q * 4]);  // self
        int j0 = row_ptr[i], j1 = j0 + deg[i];
        for (int j = j0; j < j1; ++j) {
            int s = col[j];
            float4 v = *reinterpret_cast<const float4*>(&h2p[(size_t)s * HID + q * 4]);
            acc.x += v.x; acc.y += v.y; acc.z += v.z; acc.w += v.w;
        }
        float di = dinv[i];
        as[nl][q * 4 + 0] = di * acc.x;
        as[nl][q * 4 + 1] = di * acc.y;
        as[nl][q * 4 + 2] = di * acc.z;
        as[nl][q * 4 + 3] = di * acc.w;
    } else {
        as[nl][q * 4 + 0] = 0.f;
        as[nl][q * 4 + 1] = 0.f;
        as[nl][q * 4 + 2] = 0.f;
        as[nl][q * 4 + 3] = 0.f;
    }
    __syncthreads();
    int g = q;  // col group: cols g*16 .. g*16+15
    float r[16];
#pragma unroll
    for (int c = 0; c < 16; ++c) r[c] = b2[g * 16 + c];
#pragma unroll
    for (int k = 0; k < HID; ++k) {
        float a = as[nl][k];
#pragma unroll
        for (int c = 0; c < 16; ++c) r[c] = fmaf(a, Ws[k * OUT_CH + g * 16 + c], r[c]);
    }
    if (i < n) {
        float4* o = reinterpret_cast<float4*>(&out[(size_t)i * OUT_CH + g * 16]);
        o[0] = make_float4(r[0], r[1], r[2], r[3]);
        o[1] = make_float4(r[4], r[5], r[6], r[7]);
        o[2] = make_float4(r[8], r[9], r[10], r[11]);
        o[3] = make_float4(r[12], r[13], r[14], r[15]);
    }
}

extern "C" void kernel_launch(void* const* d_in, const int* in_sizes, int n_in,
                              void* d_out, int out_size, void* d_ws, size_t ws_size,
                              hipStream_t stream) {
    const float* x  = (const float*)d_in[0];
    const int*   ei = (const int*)d_in[1];
    const float* W1 = (const float*)d_in[2];
    const float* b1 = (const float*)d_in[3];
    const float* W2 = (const float*)d_in[4];
    const float* b2 = (const float*)d_in[5];
    float* out = (float*)d_out;

    const int* src = ei;
    const int* dst = ei + N_EDGES;

    // workspace layout (4B units)
    int*      hist    = (int*)d_ws;                    // [0, 800)
    int*      bse     = hist + 800;                    // [800, 1600)
    int*      cur     = bse + 800;                     // [1600, 2400)
    int*      row_ptr = cur + 800;                     // [2400, 102400)
    int*      deg     = row_ptr + N_NODES;             // [102400, 202400)
    float*    dinv    = (float*)(deg + N_NODES);       // [202400, 302400)
    int*      col     = (int*)(dinv + N_NODES);        // [302400, 3502400)
    float*    h1p     = (float*)(col + N_EDGES);       // [3502400, 5102400)
    unsigned* colp    = (unsigned*)(h1p + (size_t)N_NODES * HID);  // [5102400, 8302400)
    float*    h2p     = (float*)colp;                  // aliases colp (dead after k_build)

    // build bucketed edge list
    hipMemsetAsync(hist, 0, NBUCK * sizeof(int), stream);
    k_hist0<<<(N_EDGES + 8191) / 8192, 256, 0, stream>>>(dst, hist, N_EDGES);
    k_scan0<<<1, 1024, 0, stream>>>(hist, bse, cur);
    k_bucket<<<(N_EDGES + 2047) / 2048, 256, 0, stream>>>(src, dst, cur, colp, N_EDGES);
    // per-bucket counting sort -> full CSR + degrees + dinv
    k_build<<<NBUCK, 256, 0, stream>>>(colp, bse, hist, col, row_ptr, deg, dinv);

    // h1' = dinv * (x @ W1)
    k_gemm1<<<(N_NODES + 15) / 16, 256, 0, stream>>>(x, W1, dinv, h1p, N_NODES);

    // layer 1: gather + bias + relu + pre-scale   (h2p aliases colp region; colp is dead)
    k_gather1<<<((size_t)4 * N_NODES + 255) / 256, 256, 0, stream>>>(h1p, row_ptr, deg, dinv, col,
                                                                     b1, h2p, N_NODES);

    // layer 2: gather fused with final GEMM + bias
    k_gather2_out<<<(N_NODES + 63) / 64, 256, 0, stream>>>(h2p, row_ptr, deg, dinv, col, W2, b2,
                                                           out, N_NODES);
}

// Round 5
// 237.433 us; speedup vs baseline: 3.4464x; 1.1505x over previous
//
#include <hip/hip_runtime.h>
#include <hip/hip_bf16.h>

#define N_NODES 100000
#define N_EDGES 3200000
#define IN_CH 128
#define HID 16
#define OUT_CH 64
#define BSHIFT 7
#define BNODES 128              // nodes per bucket
#define NBUCK 782               // ceil(100000/128)

__device__ __forceinline__ float bf2f(unsigned short u) {
    union { unsigned v; float f; } t; t.v = ((unsigned)u) << 16; return t.f;
}
__device__ __forceinline__ unsigned short f2bf(float f) {
    union { float f; unsigned v; } t; t.f = f;
    unsigned r = t.v + 0x7FFFu + ((t.v >> 16) & 1u);   // round-to-nearest-even
    return (unsigned short)(r >> 16);
}

// ---------------- pass 0: global bucket histogram (LDS-privatized) ----------------
__global__ __launch_bounds__(256) void k_hist0(const int* __restrict__ dst, int* __restrict__ hist, int e) {
    __shared__ int lh[NBUCK];
    int t = threadIdx.x;
    for (int i = t; i < NBUCK; i += 256) lh[i] = 0;
    __syncthreads();
    int base = blockIdx.x * 8192;
    for (int j = 0; j < 32; ++j) {
        int idx = base + j * 256 + t;
        if (idx < e) atomicAdd(&lh[dst[idx] >> BSHIFT], 1);
    }
    __syncthreads();
    for (int i = t; i < NBUCK; i += 256) if (lh[i]) atomicAdd(&hist[i], lh[i]);
}

// ---------------- scan 782 bucket counts -> base + cursor ----------------
__global__ __launch_bounds__(1024) void k_scan0(const int* __restrict__ hist, int* __restrict__ bse,
                                                int* __restrict__ cur) {
    __shared__ int sh[1024];
    int t = threadIdx.x;
    int v = (t < NBUCK) ? hist[t] : 0;
    sh[t] = v;
    __syncthreads();
    for (int off = 1; off < 1024; off <<= 1) {
        int x = (t >= off) ? sh[t - off] : 0;
        __syncthreads();
        sh[t] += x;
        __syncthreads();
    }
    if (t < NBUCK) { int ex = sh[t] - v; bse[t] = ex; cur[t] = ex; }
}

// ---------------- pass 1: scatter packed edges into bucket runs (block-coalesced) ----------------
__global__ __launch_bounds__(256) void k_bucket(const int* __restrict__ src, const int* __restrict__ dst,
                                                int* __restrict__ cur, unsigned* __restrict__ colp, int e) {
    __shared__ int lh[NBUCK];
    __shared__ int lb[NBUCK];
    int t = threadIdx.x;
    for (int i = t; i < NBUCK; i += 256) lh[i] = 0;
    __syncthreads();
    int base = blockIdx.x * 2048;
    int bk[8]; int rk[8]; unsigned pk[8];
#pragma unroll
    for (int j = 0; j < 8; ++j) {
        int idx = base + j * 256 + t;
        if (idx < e) {
            int d = dst[idx];
            int b = d >> BSHIFT;
            bk[j] = b;
            pk[j] = ((unsigned)(d & (BNODES - 1)) << 17) | (unsigned)src[idx];
            rk[j] = atomicAdd(&lh[b], 1);
        } else bk[j] = -1;
    }
    __syncthreads();
    for (int i = t; i < NBUCK; i += 256) { int c = lh[i]; lb[i] = c ? atomicAdd(&cur[i], c) : 0; }
    __syncthreads();
#pragma unroll
    for (int j = 0; j < 8; ++j) if (bk[j] >= 0) colp[lb[bk[j]] + rk[j]] = pk[j];
}

// ---------------- pass 2: per-bucket counting sort -> CSR (col, row_ptr, deg, dinv) ----------------
__global__ __launch_bounds__(256) void k_build(const unsigned* __restrict__ colp, const int* __restrict__ bse,
                                               const int* __restrict__ hist, int* __restrict__ col,
                                               int* __restrict__ row_ptr, int* __restrict__ deg,
                                               float* __restrict__ dinv) {
    __shared__ int cnt[BNODES];
    __shared__ int sc[BNODES];
    __shared__ int ex[BNODES];
    __shared__ int curl[BNODES];
    int b = blockIdx.x, t = threadIdx.x;
    if (t < BNODES) cnt[t] = 0;
    __syncthreads();
    int base = bse[b], m = hist[b];
    for (int i = t; i < m; i += 256) atomicAdd(&cnt[colp[base + i] >> 17], 1);
    __syncthreads();
    if (t < BNODES) sc[t] = cnt[t];
    __syncthreads();
    for (int off = 1; off < BNODES; off <<= 1) {
        int x = 0;
        if (t < BNODES && t >= off) x = sc[t - off];
        __syncthreads();
        if (t < BNODES) sc[t] += x;
        __syncthreads();
    }
    if (t < BNODES) {
        ex[t] = sc[t] - cnt[t];
        curl[t] = 0;
        int node = b * BNODES + t;
        if (node < N_NODES) {
            row_ptr[node] = base + ex[t];
            deg[node] = cnt[t];
            dinv[node] = rsqrtf((float)cnt[t] + 1.0f);
        }
    }
    __syncthreads();
    for (int i = t; i < m; i += 256) {
        unsigned v = colp[base + i];
        int l = v >> 17;
        int p = atomicAdd(&curl[l], 1);
        col[base + ex[l] + p] = (int)(v & 0x1FFFF);
    }
}

// ---------------- h1' = bf16( dinv * (x @ W1) )  (N x 128) @ (128 x 16) ----------------
__global__ __launch_bounds__(256) void k_gemm1(const float* __restrict__ x,
                                               const float* __restrict__ W1,
                                               const float* __restrict__ dinv,
                                               unsigned short* __restrict__ h1p, int n) {
    __shared__ float Ws[IN_CH * HID];
    __shared__ float xs[16][IN_CH + 1];
    int tid = threadIdx.x;
    for (int i = tid; i < IN_CH * HID; i += 256) Ws[i] = W1[i];
    int row0 = blockIdx.x * 16;
    for (int i = tid; i < 16 * IN_CH; i += 256) {
        int r = i / IN_CH, c = i % IN_CH;
        int row = row0 + r;
        xs[r][c] = (row < n) ? x[(size_t)row * IN_CH + c] : 0.f;
    }
    __syncthreads();
    int r = tid >> 4, c = tid & 15;
    float acc = 0.f;
#pragma unroll
    for (int k = 0; k < IN_CH; ++k) acc = fmaf(xs[r][k], Ws[k * HID + c], acc);
    int row = row0 + r;
    if (row < n) h1p[(size_t)row * HID + c] = f2bf(dinv[row] * acc);
}

// ---------------- gather layer 1 (bf16 features, f32 accum) ----------------
// h2' = bf16( dinv * relu(dinv*(h1p[i] + sum h1p[col]) + b1) )
__global__ __launch_bounds__(256) void k_gather1(const unsigned short* __restrict__ h1p,
                                                 const int* __restrict__ row_ptr,
                                                 const int* __restrict__ deg,
                                                 const float* __restrict__ dinv,
                                                 const int* __restrict__ col,
                                                 const float* __restrict__ b1,
                                                 unsigned short* __restrict__ h2p, int n) {
    int t = blockIdx.x * blockDim.x + threadIdx.x;
    int i = t >> 2, q = t & 3;
    if (i >= n) return;
    ushort4 hv = *reinterpret_cast<const ushort4*>(&h1p[(size_t)i * HID + q * 4]);
    float ax = bf2f(hv.x), ay = bf2f(hv.y), az = bf2f(hv.z), aw = bf2f(hv.w);
    int j0 = row_ptr[i], j1 = j0 + deg[i];
    int j = j0;
    for (; j + 1 < j1; j += 2) {
        int s0 = col[j], s1 = col[j + 1];
        ushort4 v0 = *reinterpret_cast<const ushort4*>(&h1p[(size_t)s0 * HID + q * 4]);
        ushort4 v1 = *reinterpret_cast<const ushort4*>(&h1p[(size_t)s1 * HID + q * 4]);
        ax += bf2f(v0.x) + bf2f(v1.x);
        ay += bf2f(v0.y) + bf2f(v1.y);
        az += bf2f(v0.z) + bf2f(v1.z);
        aw += bf2f(v0.w) + bf2f(v1.w);
    }
    if (j < j1) {
        int s = col[j];
        ushort4 v = *reinterpret_cast<const ushort4*>(&h1p[(size_t)s * HID + q * 4]);
        ax += bf2f(v.x); ay += bf2f(v.y); az += bf2f(v.z); aw += bf2f(v.w);
    }
    float di = dinv[i];
    float4 b = *reinterpret_cast<const float4*>(&b1[q * 4]);
    ushort4 o;
    o.x = f2bf(di * fmaxf(fmaf(di, ax, b.x), 0.f));
    o.y = f2bf(di * fmaxf(fmaf(di, ay, b.y), 0.f));
    o.z = f2bf(di * fmaxf(fmaf(di, az, b.z), 0.f));
    o.w = f2bf(di * fmaxf(fmaf(di, aw, b.w), 0.f));
    *reinterpret_cast<ushort4*>(&h2p[(size_t)i * HID + q * 4]) = o;
}

// ---------------- gather layer 2 (bf16) fused with (N x 16)@(16 x 64) + b2 ----------------
__global__ __launch_bounds__(256) void k_gather2_out(const unsigned short* __restrict__ h2p,
                                                     const int* __restrict__ row_ptr,
                                                     const int* __restrict__ deg,
                                                     const float* __restrict__ dinv,
                                                     const int* __restrict__ col,
                                                     const float* __restrict__ W2,
                                                     const float* __restrict__ b2,
                                                     float* __restrict__ out, int n) {
    __shared__ float Ws[HID * OUT_CH];   // 1024 f
    __shared__ float as[64][HID + 1];    // padded
    int t = threadIdx.x;
    for (int i = t; i < HID * OUT_CH; i += 256) Ws[i] = W2[i];
    int i0 = blockIdx.x * 64;
    int nl = t >> 2, q = t & 3;
    int i = i0 + nl;
    if (i < n) {
        ushort4 hv = *reinterpret_cast<const ushort4*>(&h2p[(size_t)i * HID + q * 4]);
        float ax = bf2f(hv.x), ay = bf2f(hv.y), az = bf2f(hv.z), aw = bf2f(hv.w);
        int j0 = row_ptr[i], j1 = j0 + deg[i];
        int j = j0;
        for (; j + 1 < j1; j += 2) {
            int s0 = col[j], s1 = col[j + 1];
            ushort4 v0 = *reinterpret_cast<const ushort4*>(&h2p[(size_t)s0 * HID + q * 4]);
            ushort4 v1 = *reinterpret_cast<const ushort4*>(&h2p[(size_t)s1 * HID + q * 4]);
            ax += bf2f(v0.x) + bf2f(v1.x);
            ay += bf2f(v0.y) + bf2f(v1.y);
            az += bf2f(v0.z) + bf2f(v1.z);
            aw += bf2f(v0.w) + bf2f(v1.w);
        }
        if (j < j1) {
            int s = col[j];
            ushort4 v = *reinterpret_cast<const ushort4*>(&h2p[(size_t)s * HID + q * 4]);
            ax += bf2f(v.x); ay += bf2f(v.y); az += bf2f(v.z); aw += bf2f(v.w);
        }
        float di = dinv[i];
        as[nl][q * 4 + 0] = di * ax;
        as[nl][q * 4 + 1] = di * ay;
        as[nl][q * 4 + 2] = di * az;
        as[nl][q * 4 + 3] = di * aw;
    } else {
        as[nl][q * 4 + 0] = 0.f;
        as[nl][q * 4 + 1] = 0.f;
        as[nl][q * 4 + 2] = 0.f;
        as[nl][q * 4 + 3] = 0.f;
    }
    __syncthreads();
    int g = q;  // col group: cols g*16 .. g*16+15
    float r[16];
#pragma unroll
    for (int c = 0; c < 16; ++c) r[c] = b2[g * 16 + c];
#pragma unroll
    for (int k = 0; k < HID; ++k) {
        float a = as[nl][k];
#pragma unroll
        for (int c = 0; c < 16; ++c) r[c] = fmaf(a, Ws[k * OUT_CH + g * 16 + c], r[c]);
    }
    if (i < n) {
        float4* o = reinterpret_cast<float4*>(&out[(size_t)i * OUT_CH + g * 16]);
        o[0] = make_float4(r[0], r[1], r[2], r[3]);
        o[1] = make_float4(r[4], r[5], r[6], r[7]);
        o[2] = make_float4(r[8], r[9], r[10], r[11]);
        o[3] = make_float4(r[12], r[13], r[14], r[15]);
    }
}

extern "C" void kernel_launch(void* const* d_in, const int* in_sizes, int n_in,
                              void* d_out, int out_size, void* d_ws, size_t ws_size,
                              hipStream_t stream) {
    const float* x  = (const float*)d_in[0];
    const int*   ei = (const int*)d_in[1];
    const float* W1 = (const float*)d_in[2];
    const float* b1 = (const float*)d_in[3];
    const float* W2 = (const float*)d_in[4];
    const float* b2 = (const float*)d_in[5];
    float* out = (float*)d_out;

    const int* src = ei;
    const int* dst = ei + N_EDGES;

    // workspace layout (4B units)
    int*            hist    = (int*)d_ws;                         // [0, 800)
    int*            bse     = hist + 800;                         // [800, 1600)
    int*            cur     = bse + 800;                          // [1600, 2400)
    int*            row_ptr = cur + 800;                          // [2400, 102400)
    int*            deg     = row_ptr + N_NODES;                  // [102400, 202400)
    float*          dinv    = (float*)(deg + N_NODES);            // [202400, 302400)
    int*            col     = (int*)(dinv + N_NODES);             // [302400, 3502400)
    unsigned short* h1p     = (unsigned short*)(col + N_EDGES);   // [3502400, 4302400)  bf16 N*16
    unsigned*       colp    = (unsigned*)((int*)col + N_EDGES + 800000);  // [4302400, 7502400)
    unsigned short* h2p     = (unsigned short*)colp;              // aliases colp (dead after k_build)

    // build bucketed edge list
    hipMemsetAsync(hist, 0, NBUCK * sizeof(int), stream);
    k_hist0<<<(N_EDGES + 8191) / 8192, 256, 0, stream>>>(dst, hist, N_EDGES);
    k_scan0<<<1, 1024, 0, stream>>>(hist, bse, cur);
    k_bucket<<<(N_EDGES + 2047) / 2048, 256, 0, stream>>>(src, dst, cur, colp, N_EDGES);
    // per-bucket counting sort -> full CSR + degrees + dinv
    k_build<<<NBUCK, 256, 0, stream>>>(colp, bse, hist, col, row_ptr, deg, dinv);

    // h1' = bf16(dinv * (x @ W1))
    k_gemm1<<<(N_NODES + 15) / 16, 256, 0, stream>>>(x, W1, dinv, h1p, N_NODES);

    // layer 1: gather + bias + relu + pre-scale  (h2p aliases colp region; colp dead)
    k_gather1<<<((size_t)4 * N_NODES + 255) / 256, 256, 0, stream>>>(h1p, row_ptr, deg, dinv, col,
                                                                     b1, h2p, N_NODES);

    // layer 2: gather fused with final GEMM + bias
    k_gather2_out<<<(N_NODES + 63) / 64, 256, 0, stream>>>(h2p, row_ptr, deg, dinv, col, W2, b2,
                                                           out, N_NODES);
}

// Round 6
// 228.055 us; speedup vs baseline: 3.5881x; 1.0411x over previous
//
#include <hip/hip_runtime.h>
#include <hip/hip_bf16.h>

#define N_NODES 100000
#define N_EDGES 3200000
#define IN_CH 128
#define HID 16
#define OUT_CH 64
#define BSHIFT 10
#define BNODES 1024             // nodes per bucket
#define NBUCK 98                // ceil(100000/1024)

__device__ __forceinline__ float bf2f(unsigned short u) {
    union { unsigned v; float f; } t; t.v = ((unsigned)u) << 16; return t.f;
}
__device__ __forceinline__ unsigned short f2bf(float f) {
    union { float f; unsigned v; } t; t.f = f;
    unsigned r = t.v + 0x7FFFu + ((t.v >> 16) & 1u);   // round-to-nearest-even
    return (unsigned short)(r >> 16);
}

// ---------------- pass 0: global bucket histogram (LDS-privatized) ----------------
__global__ __launch_bounds__(256) void k_hist0(const int* __restrict__ dst, int* __restrict__ hist, int e) {
    __shared__ int lh[NBUCK];
    int t = threadIdx.x;
    if (t < NBUCK) lh[t] = 0;
    __syncthreads();
    int base = blockIdx.x * 8192;
    for (int j = 0; j < 32; ++j) {
        int idx = base + j * 256 + t;
        if (idx < e) atomicAdd(&lh[dst[idx] >> BSHIFT], 1);
    }
    __syncthreads();
    if (t < NBUCK && lh[t]) atomicAdd(&hist[t], lh[t]);
}

// ---------------- scan 98 bucket counts -> base + cursor ----------------
__global__ __launch_bounds__(128) void k_scan0(const int* __restrict__ hist, int* __restrict__ bse,
                                               int* __restrict__ cur) {
    __shared__ int sh[128];
    int t = threadIdx.x;
    int v = (t < NBUCK) ? hist[t] : 0;
    sh[t] = v;
    __syncthreads();
    for (int off = 1; off < 128; off <<= 1) {
        int x = (t >= off) ? sh[t - off] : 0;
        __syncthreads();
        sh[t] += x;
        __syncthreads();
    }
    if (t < NBUCK) { int ex = sh[t] - v; bse[t] = ex; cur[t] = ex; }
}

// ---------------- pass 1: scatter packed edges into bucket runs (block-coalesced) ----------------
// 4096 edges/block over 98 buckets -> runs of ~42 edges (~168B) -> write amp ~1.4x
__global__ __launch_bounds__(256) void k_bucket(const int* __restrict__ src, const int* __restrict__ dst,
                                                int* __restrict__ cur, unsigned* __restrict__ colp, int e) {
    __shared__ int lh[NBUCK];
    __shared__ int lb[NBUCK];
    int t = threadIdx.x;
    if (t < NBUCK) lh[t] = 0;
    __syncthreads();
    int base = blockIdx.x * 4096;
    int bk[16]; int rk[16]; unsigned pk[16];
#pragma unroll
    for (int j = 0; j < 16; ++j) {
        int idx = base + j * 256 + t;
        if (idx < e) {
            int d = dst[idx];
            int b = d >> BSHIFT;
            bk[j] = b;
            pk[j] = ((unsigned)(d & (BNODES - 1)) << 17) | (unsigned)src[idx];
            rk[j] = atomicAdd(&lh[b], 1);
        } else bk[j] = -1;
    }
    __syncthreads();
    if (t < NBUCK) { int c = lh[t]; lb[t] = c ? atomicAdd(&cur[t], c) : 0; }
    __syncthreads();
#pragma unroll
    for (int j = 0; j < 16; ++j) if (bk[j] >= 0) colp[lb[bk[j]] + rk[j]] = pk[j];
}

// ---------------- pass 2: per-bucket counting sort -> CSR (col, row_ptr, deg, dinv) ----------------
// One 1024-thread block per bucket (16 waves). Scatter region ~132KB stays L2-resident
// for the block's lifetime, so 4B stores merge into full lines.
__global__ __launch_bounds__(1024) void k_build(const unsigned* __restrict__ colp, const int* __restrict__ bse,
                                                const int* __restrict__ hist, int* __restrict__ col,
                                                int* __restrict__ row_ptr, int* __restrict__ deg,
                                                float* __restrict__ dinv) {
    __shared__ int cnt[BNODES];
    __shared__ int sc[BNODES];
    __shared__ int ex[BNODES];
    __shared__ int curl[BNODES];
    int b = blockIdx.x, t = threadIdx.x;
    cnt[t] = 0;
    __syncthreads();
    int base = bse[b], m = hist[b];
    for (int i = t; i < m; i += 1024) atomicAdd(&cnt[colp[base + i] >> 17], 1);
    __syncthreads();
    int v = cnt[t];
    sc[t] = v;
    __syncthreads();
    for (int off = 1; off < BNODES; off <<= 1) {
        int x = (t >= off) ? sc[t - off] : 0;
        __syncthreads();
        sc[t] += x;
        __syncthreads();
    }
    {
        ex[t] = sc[t] - v;
        curl[t] = 0;
        int node = b * BNODES + t;
        if (node < N_NODES) {
            row_ptr[node] = base + ex[t];
            deg[node] = v;
            dinv[node] = rsqrtf((float)v + 1.0f);
        }
    }
    __syncthreads();
    for (int i = t; i < m; i += 1024) {
        unsigned pv = colp[base + i];
        int l = pv >> 17;
        int p = atomicAdd(&curl[l], 1);
        col[base + ex[l] + p] = (int)(pv & 0x1FFFF);
    }
}

// ---------------- h1' = bf16( dinv * (x @ W1) )  (N x 128) @ (128 x 16) ----------------
__global__ __launch_bounds__(256) void k_gemm1(const float* __restrict__ x,
                                               const float* __restrict__ W1,
                                               const float* __restrict__ dinv,
                                               unsigned short* __restrict__ h1p, int n) {
    __shared__ float Ws[IN_CH * HID];
    __shared__ float xs[16][IN_CH + 1];
    int tid = threadIdx.x;
    for (int i = tid; i < IN_CH * HID; i += 256) Ws[i] = W1[i];
    int row0 = blockIdx.x * 16;
    for (int i = tid; i < 16 * IN_CH; i += 256) {
        int r = i / IN_CH, c = i % IN_CH;
        int row = row0 + r;
        xs[r][c] = (row < n) ? x[(size_t)row * IN_CH + c] : 0.f;
    }
    __syncthreads();
    int r = tid >> 4, c = tid & 15;
    float acc = 0.f;
#pragma unroll
    for (int k = 0; k < IN_CH; ++k) acc = fmaf(xs[r][k], Ws[k * HID + c], acc);
    int row = row0 + r;
    if (row < n) h1p[(size_t)row * HID + c] = f2bf(dinv[row] * acc);
}

// ---------------- gather layer 1 (bf16 features, f32 accum) ----------------
__global__ __launch_bounds__(256) void k_gather1(const unsigned short* __restrict__ h1p,
                                                 const int* __restrict__ row_ptr,
                                                 const int* __restrict__ deg,
                                                 const float* __restrict__ dinv,
                                                 const int* __restrict__ col,
                                                 const float* __restrict__ b1,
                                                 unsigned short* __restrict__ h2p, int n) {
    int t = blockIdx.x * blockDim.x + threadIdx.x;
    int i = t >> 2, q = t & 3;
    if (i >= n) return;
    ushort4 hv = *reinterpret_cast<const ushort4*>(&h1p[(size_t)i * HID + q * 4]);
    float ax = bf2f(hv.x), ay = bf2f(hv.y), az = bf2f(hv.z), aw = bf2f(hv.w);
    int j0 = row_ptr[i], j1 = j0 + deg[i];
    int j = j0;
    for (; j + 1 < j1; j += 2) {
        int s0 = col[j], s1 = col[j + 1];
        ushort4 v0 = *reinterpret_cast<const ushort4*>(&h1p[(size_t)s0 * HID + q * 4]);
        ushort4 v1 = *reinterpret_cast<const ushort4*>(&h1p[(size_t)s1 * HID + q * 4]);
        ax += bf2f(v0.x) + bf2f(v1.x);
        ay += bf2f(v0.y) + bf2f(v1.y);
        az += bf2f(v0.z) + bf2f(v1.z);
        aw += bf2f(v0.w) + bf2f(v1.w);
    }
    if (j < j1) {
        int s = col[j];
        ushort4 v = *reinterpret_cast<const ushort4*>(&h1p[(size_t)s * HID + q * 4]);
        ax += bf2f(v.x); ay += bf2f(v.y); az += bf2f(v.z); aw += bf2f(v.w);
    }
    float di = dinv[i];
    float4 b = *reinterpret_cast<const float4*>(&b1[q * 4]);
    ushort4 o;
    o.x = f2bf(di * fmaxf(fmaf(di, ax, b.x), 0.f));
    o.y = f2bf(di * fmaxf(fmaf(di, ay, b.y), 0.f));
    o.z = f2bf(di * fmaxf(fmaf(di, az, b.z), 0.f));
    o.w = f2bf(di * fmaxf(fmaf(di, aw, b.w), 0.f));
    *reinterpret_cast<ushort4*>(&h2p[(size_t)i * HID + q * 4]) = o;
}

// ---------------- gather layer 2 (bf16) fused with (N x 16)@(16 x 64) + b2 ----------------
__global__ __launch_bounds__(256) void k_gather2_out(const unsigned short* __restrict__ h2p,
                                                     const int* __restrict__ row_ptr,
                                                     const int* __restrict__ deg,
                                                     const float* __restrict__ dinv,
                                                     const int* __restrict__ col,
                                                     const float* __restrict__ W2,
                                                     const float* __restrict__ b2,
                                                     float* __restrict__ out, int n) {
    __shared__ float Ws[HID * OUT_CH];   // 1024 f
    __shared__ float as[64][HID + 1];    // padded
    int t = threadIdx.x;
    for (int i = t; i < HID * OUT_CH; i += 256) Ws[i] = W2[i];
    int i0 = blockIdx.x * 64;
    int nl = t >> 2, q = t & 3;
    int i = i0 + nl;
    if (i < n) {
        ushort4 hv = *reinterpret_cast<const ushort4*>(&h2p[(size_t)i * HID + q * 4]);
        float ax = bf2f(hv.x), ay = bf2f(hv.y), az = bf2f(hv.z), aw = bf2f(hv.w);
        int j0 = row_ptr[i], j1 = j0 + deg[i];
        int j = j0;
        for (; j + 1 < j1; j += 2) {
            int s0 = col[j], s1 = col[j + 1];
            ushort4 v0 = *reinterpret_cast<const ushort4*>(&h2p[(size_t)s0 * HID + q * 4]);
            ushort4 v1 = *reinterpret_cast<const ushort4*>(&h2p[(size_t)s1 * HID + q * 4]);
            ax += bf2f(v0.x) + bf2f(v1.x);
            ay += bf2f(v0.y) + bf2f(v1.y);
            az += bf2f(v0.z) + bf2f(v1.z);
            aw += bf2f(v0.w) + bf2f(v1.w);
        }
        if (j < j1) {
            int s = col[j];
            ushort4 v = *reinterpret_cast<const ushort4*>(&h2p[(size_t)s * HID + q * 4]);
            ax += bf2f(v.x); ay += bf2f(v.y); az += bf2f(v.z); aw += bf2f(v.w);
        }
        float di = dinv[i];
        as[nl][q * 4 + 0] = di * ax;
        as[nl][q * 4 + 1] = di * ay;
        as[nl][q * 4 + 2] = di * az;
        as[nl][q * 4 + 3] = di * aw;
    } else {
        as[nl][q * 4 + 0] = 0.f;
        as[nl][q * 4 + 1] = 0.f;
        as[nl][q * 4 + 2] = 0.f;
        as[nl][q * 4 + 3] = 0.f;
    }
    __syncthreads();
    int g = q;  // col group: cols g*16 .. g*16+15
    float r[16];
#pragma unroll
    for (int c = 0; c < 16; ++c) r[c] = b2[g * 16 + c];
#pragma unroll
    for (int k = 0; k < HID; ++k) {
        float a = as[nl][k];
#pragma unroll
        for (int c = 0; c < 16; ++c) r[c] = fmaf(a, Ws[k * OUT_CH + g * 16 + c], r[c]);
    }
    if (i < n) {
        float4* o = reinterpret_cast<float4*>(&out[(size_t)i * OUT_CH + g * 16]);
        o[0] = make_float4(r[0], r[1], r[2], r[3]);
        o[1] = make_float4(r[4], r[5], r[6], r[7]);
        o[2] = make_float4(r[8], r[9], r[10], r[11]);
        o[3] = make_float4(r[12], r[13], r[14], r[15]);
    }
}

extern "C" void kernel_launch(void* const* d_in, const int* in_sizes, int n_in,
                              void* d_out, int out_size, void* d_ws, size_t ws_size,
                              hipStream_t stream) {
    const float* x  = (const float*)d_in[0];
    const int*   ei = (const int*)d_in[1];
    const float* W1 = (const float*)d_in[2];
    const float* b1 = (const float*)d_in[3];
    const float* W2 = (const float*)d_in[4];
    const float* b2 = (const float*)d_in[5];
    float* out = (float*)d_out;

    const int* src = ei;
    const int* dst = ei + N_EDGES;

    // workspace layout (4B units)
    int*            hist    = (int*)d_ws;                         // [0, 800)
    int*            bse     = hist + 800;                         // [800, 1600)
    int*            cur     = bse + 800;                          // [1600, 2400)
    int*            row_ptr = cur + 800;                          // [2400, 102400)
    int*            deg     = row_ptr + N_NODES;                  // [102400, 202400)
    float*          dinv    = (float*)(deg + N_NODES);            // [202400, 302400)
    int*            col     = (int*)(dinv + N_NODES);             // [302400, 3502400)
    unsigned short* h1p     = (unsigned short*)(col + N_EDGES);   // [3502400, 4302400)  bf16 N*16
    unsigned*       colp    = (unsigned*)((int*)col + N_EDGES + 800000);  // [4302400, 7502400)
    unsigned short* h2p     = (unsigned short*)colp;              // aliases colp (dead after k_build)

    // build bucketed edge list
    hipMemsetAsync(hist, 0, NBUCK * sizeof(int), stream);
    k_hist0<<<(N_EDGES + 8191) / 8192, 256, 0, stream>>>(dst, hist, N_EDGES);
    k_scan0<<<1, 128, 0, stream>>>(hist, bse, cur);
    k_bucket<<<(N_EDGES + 4095) / 4096, 256, 0, stream>>>(src, dst, cur, colp, N_EDGES);
    // per-bucket counting sort -> full CSR + degrees + dinv
    k_build<<<NBUCK, 1024, 0, stream>>>(colp, bse, hist, col, row_ptr, deg, dinv);

    // h1' = bf16(dinv * (x @ W1))
    k_gemm1<<<(N_NODES + 15) / 16, 256, 0, stream>>>(x, W1, dinv, h1p, N_NODES);

    // layer 1: gather + bias + relu + pre-scale  (h2p aliases colp region; colp dead)
    k_gather1<<<((size_t)4 * N_NODES + 255) / 256, 256, 0, stream>>>(h1p, row_ptr, deg, dinv, col,
                                                                     b1, h2p, N_NODES);

    // layer 2: gather fused with final GEMM + bias
    k_gather2_out<<<(N_NODES + 63) / 64, 256, 0, stream>>>(h2p, row_ptr, deg, dinv, col, W2, b2,
                                                           out, N_NODES);
}

// Round 7
// 221.823 us; speedup vs baseline: 3.6889x; 1.0281x over previous
//
#include <hip/hip_runtime.h>
#include <hip/hip_bf16.h>

#define N_NODES 100000
#define N_EDGES 3200000
#define IN_CH 128
#define HID 16
#define OUT_CH 64
#define BSHIFT 10
#define BNODES 1024             // nodes per bucket
#define NBUCK 98                // ceil(100000/1024)

__device__ __forceinline__ float bf2f(unsigned short u) {
    union { unsigned v; float f; } t; t.v = ((unsigned)u) << 16; return t.f;
}
__device__ __forceinline__ unsigned short f2bf(float f) {
    union { float f; unsigned v; } t; t.f = f;
    unsigned r = t.v + 0x7FFFu + ((t.v >> 16) & 1u);   // round-to-nearest-even
    return (unsigned short)(r >> 16);
}
__device__ __forceinline__ unsigned pack2(float lo, float hi) {
    return (unsigned)f2bf(lo) | ((unsigned)f2bf(hi) << 16);
}
// accumulate 8 bf16 channels packed in a uint4 into a[0..7]
__device__ __forceinline__ void acc8(uint4 v, float* a) {
    union { unsigned u; float f; } c;
    c.u = v.x << 16;         a[0] += c.f;
    c.u = v.x & 0xffff0000u; a[1] += c.f;
    c.u = v.y << 16;         a[2] += c.f;
    c.u = v.y & 0xffff0000u; a[3] += c.f;
    c.u = v.z << 16;         a[4] += c.f;
    c.u = v.z & 0xffff0000u; a[5] += c.f;
    c.u = v.w << 16;         a[6] += c.f;
    c.u = v.w & 0xffff0000u; a[7] += c.f;
}

// ---------------- pass 0: global bucket histogram (LDS-privatized) ----------------
__global__ __launch_bounds__(256) void k_hist0(const int* __restrict__ dst, int* __restrict__ hist, int e) {
    __shared__ int lh[NBUCK];
    int t = threadIdx.x;
    if (t < NBUCK) lh[t] = 0;
    __syncthreads();
    int base = blockIdx.x * 8192;
    for (int j = 0; j < 32; ++j) {
        int idx = base + j * 256 + t;
        if (idx < e) atomicAdd(&lh[dst[idx] >> BSHIFT], 1);
    }
    __syncthreads();
    if (t < NBUCK && lh[t]) atomicAdd(&hist[t], lh[t]);
}

// ---------------- scan 98 bucket counts -> base + cursor ----------------
__global__ __launch_bounds__(128) void k_scan0(const int* __restrict__ hist, int* __restrict__ bse,
                                               int* __restrict__ cur) {
    __shared__ int sh[128];
    int t = threadIdx.x;
    int v = (t < NBUCK) ? hist[t] : 0;
    sh[t] = v;
    __syncthreads();
    for (int off = 1; off < 128; off <<= 1) {
        int x = (t >= off) ? sh[t - off] : 0;
        __syncthreads();
        sh[t] += x;
        __syncthreads();
    }
    if (t < NBUCK) { int ex = sh[t] - v; bse[t] = ex; cur[t] = ex; }
}

// ---------------- pass 1: scatter packed edges into bucket runs (block-coalesced) ----------------
__global__ __launch_bounds__(256) void k_bucket(const int* __restrict__ src, const int* __restrict__ dst,
                                                int* __restrict__ cur, unsigned* __restrict__ colp, int e) {
    __shared__ int lh[NBUCK];
    __shared__ int lb[NBUCK];
    int t = threadIdx.x;
    if (t < NBUCK) lh[t] = 0;
    __syncthreads();
    int base = blockIdx.x * 4096;
    int bk[16]; int rk[16]; unsigned pk[16];
#pragma unroll
    for (int j = 0; j < 16; ++j) {
        int idx = base + j * 256 + t;
        if (idx < e) {
            int d = dst[idx];
            int b = d >> BSHIFT;
            bk[j] = b;
            pk[j] = ((unsigned)(d & (BNODES - 1)) << 17) | (unsigned)src[idx];
            rk[j] = atomicAdd(&lh[b], 1);
        } else bk[j] = -1;
    }
    __syncthreads();
    if (t < NBUCK) { int c = lh[t]; lb[t] = c ? atomicAdd(&cur[t], c) : 0; }
    __syncthreads();
#pragma unroll
    for (int j = 0; j < 16; ++j) if (bk[j] >= 0) colp[lb[bk[j]] + rk[j]] = pk[j];
}

// ---------------- pass 2: per-bucket counting sort -> CSR (col, row_ptr, deg, dinv) ----------------
__global__ __launch_bounds__(1024) void k_build(const unsigned* __restrict__ colp, const int* __restrict__ bse,
                                                const int* __restrict__ hist, int* __restrict__ col,
                                                int* __restrict__ row_ptr, int* __restrict__ deg,
                                                float* __restrict__ dinv) {
    __shared__ int cnt[BNODES];
    __shared__ int sc[BNODES];
    __shared__ int ex[BNODES];
    __shared__ int curl[BNODES];
    int b = blockIdx.x, t = threadIdx.x;
    cnt[t] = 0;
    __syncthreads();
    int base = bse[b], m = hist[b];
    for (int i = t; i < m; i += 1024) atomicAdd(&cnt[colp[base + i] >> 17], 1);
    __syncthreads();
    int v = cnt[t];
    sc[t] = v;
    __syncthreads();
    for (int off = 1; off < BNODES; off <<= 1) {
        int x = (t >= off) ? sc[t - off] : 0;
        __syncthreads();
        sc[t] += x;
        __syncthreads();
    }
    {
        ex[t] = sc[t] - v;
        curl[t] = 0;
        int node = b * BNODES + t;
        if (node < N_NODES) {
            row_ptr[node] = base + ex[t];
            deg[node] = v;
            dinv[node] = rsqrtf((float)v + 1.0f);
        }
    }
    __syncthreads();
    for (int i = t; i < m; i += 1024) {
        unsigned pv = colp[base + i];
        int l = pv >> 17;
        int p = atomicAdd(&curl[l], 1);
        col[base + ex[l] + p] = (int)(pv & 0x1FFFF);
    }
}

// ---------------- h1' = bf16( dinv * (x @ W1) )  (N x 128) @ (128 x 16) ----------------
__global__ __launch_bounds__(256) void k_gemm1(const float* __restrict__ x,
                                               const float* __restrict__ W1,
                                               const float* __restrict__ dinv,
                                               unsigned short* __restrict__ h1p, int n) {
    __shared__ float Ws[IN_CH * HID];
    __shared__ float xs[16][IN_CH + 1];
    int tid = threadIdx.x;
    for (int i = tid; i < IN_CH * HID; i += 256) Ws[i] = W1[i];
    int row0 = blockIdx.x * 16;
    for (int i = tid; i < 16 * IN_CH; i += 256) {
        int r = i / IN_CH, c = i % IN_CH;
        int row = row0 + r;
        xs[r][c] = (row < n) ? x[(size_t)row * IN_CH + c] : 0.f;
    }
    __syncthreads();
    int r = tid >> 4, c = tid & 15;
    float acc = 0.f;
#pragma unroll
    for (int k = 0; k < IN_CH; ++k) acc = fmaf(xs[r][k], Ws[k * HID + c], acc);
    int row = row0 + r;
    if (row < n) h1p[(size_t)row * HID + c] = f2bf(dinv[row] * acc);
}

// ---------------- gather layer 1: 2 threads/node, 16B loads, 4x unroll ----------------
// h2' = bf16( dinv * relu(dinv*(h1p[i] + sum h1p[col]) + b1) )
__global__ __launch_bounds__(256) void k_gather1(const unsigned short* __restrict__ h1p,
                                                 const int* __restrict__ row_ptr,
                                                 const int* __restrict__ deg,
                                                 const float* __restrict__ dinv,
                                                 const int* __restrict__ col,
                                                 const float* __restrict__ b1,
                                                 unsigned short* __restrict__ h2p, int n) {
    int t = blockIdx.x * blockDim.x + threadIdx.x;
    int i = t >> 1, q = t & 1;                 // 2 threads/node, 8 ch each
    if (i >= n) return;
    const uint4* hp = reinterpret_cast<const uint4*>(h1p);   // row i = hp[2i], hp[2i+1]
    float a[8] = {0, 0, 0, 0, 0, 0, 0, 0};
    acc8(hp[(size_t)i * 2 + q], a);            // self-loop
    int j0 = row_ptr[i], j1 = j0 + deg[i];
    int j = j0;
    for (; j + 3 < j1; j += 4) {
        int s0 = col[j], s1 = col[j + 1], s2 = col[j + 2], s3 = col[j + 3];
        uint4 v0 = hp[(size_t)s0 * 2 + q];
        uint4 v1 = hp[(size_t)s1 * 2 + q];
        uint4 v2 = hp[(size_t)s2 * 2 + q];
        uint4 v3 = hp[(size_t)s3 * 2 + q];
        acc8(v0, a); acc8(v1, a); acc8(v2, a); acc8(v3, a);
    }
    for (; j < j1; ++j) acc8(hp[(size_t)col[j] * 2 + q], a);
    float di = dinv[i];
    float4 bl = *reinterpret_cast<const float4*>(&b1[q * 8]);
    float4 bh = *reinterpret_cast<const float4*>(&b1[q * 8 + 4]);
    float o[8];
    o[0] = di * fmaxf(fmaf(di, a[0], bl.x), 0.f);
    o[1] = di * fmaxf(fmaf(di, a[1], bl.y), 0.f);
    o[2] = di * fmaxf(fmaf(di, a[2], bl.z), 0.f);
    o[3] = di * fmaxf(fmaf(di, a[3], bl.w), 0.f);
    o[4] = di * fmaxf(fmaf(di, a[4], bh.x), 0.f);
    o[5] = di * fmaxf(fmaf(di, a[5], bh.y), 0.f);
    o[6] = di * fmaxf(fmaf(di, a[6], bh.z), 0.f);
    o[7] = di * fmaxf(fmaf(di, a[7], bh.w), 0.f);
    uint4 ov;
    ov.x = pack2(o[0], o[1]);
    ov.y = pack2(o[2], o[3]);
    ov.z = pack2(o[4], o[5]);
    ov.w = pack2(o[6], o[7]);
    reinterpret_cast<uint4*>(h2p)[(size_t)i * 2 + q] = ov;
}

// ---------------- gather layer 2 (128 nodes/block) fused with (N x 16)@(16 x 64) + b2 ----------------
__global__ __launch_bounds__(256) void k_gather2_out(const unsigned short* __restrict__ h2p,
                                                     const int* __restrict__ row_ptr,
                                                     const int* __restrict__ deg,
                                                     const float* __restrict__ dinv,
                                                     const int* __restrict__ col,
                                                     const float* __restrict__ W2,
                                                     const float* __restrict__ b2,
                                                     float* __restrict__ out, int n) {
    __shared__ float Ws[HID * OUT_CH];    // 4 KB
    __shared__ float as[128][HID + 1];    // 8.7 KB
    int t = threadIdx.x;
    for (int i = t; i < HID * OUT_CH; i += 256) Ws[i] = W2[i];
    int i0 = blockIdx.x * 128;
    int nl = t >> 1, q = t & 1;
    int i = i0 + nl;
    const uint4* hp = reinterpret_cast<const uint4*>(h2p);
    if (i < n) {
        float a[8] = {0, 0, 0, 0, 0, 0, 0, 0};
        acc8(hp[(size_t)i * 2 + q], a);    // self
        int j0 = row_ptr[i], j1 = j0 + deg[i];
        int j = j0;
        for (; j + 3 < j1; j += 4) {
            int s0 = col[j], s1 = col[j + 1], s2 = col[j + 2], s3 = col[j + 3];
            uint4 v0 = hp[(size_t)s0 * 2 + q];
            uint4 v1 = hp[(size_t)s1 * 2 + q];
            uint4 v2 = hp[(size_t)s2 * 2 + q];
            uint4 v3 = hp[(size_t)s3 * 2 + q];
            acc8(v0, a); acc8(v1, a); acc8(v2, a); acc8(v3, a);
        }
        for (; j < j1; ++j) acc8(hp[(size_t)col[j] * 2 + q], a);
        float di = dinv[i];
#pragma unroll
        for (int k = 0; k < 8; ++k) as[nl][q * 8 + k] = di * a[k];
    } else {
#pragma unroll
        for (int k = 0; k < 8; ++k) as[nl][q * 8 + k] = 0.f;
    }
    __syncthreads();
    // epilogue: node nl, cols g*32 .. g*32+31
    int g = q;
    float r[32];
#pragma unroll
    for (int c = 0; c < 32; ++c) r[c] = b2[g * 32 + c];
#pragma unroll
    for (int k = 0; k < HID; ++k) {
        float a = as[nl][k];
#pragma unroll
        for (int c = 0; c < 32; ++c) r[c] = fmaf(a, Ws[k * OUT_CH + g * 32 + c], r[c]);
    }
    if (i < n) {
        float* op = &out[(size_t)i * OUT_CH + g * 32];
#pragma unroll
        for (int c = 0; c < 32; c += 4)
            *reinterpret_cast<float4*>(&op[c]) = make_float4(r[c], r[c + 1], r[c + 2], r[c + 3]);
    }
}

extern "C" void kernel_launch(void* const* d_in, const int* in_sizes, int n_in,
                              void* d_out, int out_size, void* d_ws, size_t ws_size,
                              hipStream_t stream) {
    const float* x  = (const float*)d_in[0];
    const int*   ei = (const int*)d_in[1];
    const float* W1 = (const float*)d_in[2];
    const float* b1 = (const float*)d_in[3];
    const float* W2 = (const float*)d_in[4];
    const float* b2 = (const float*)d_in[5];
    float* out = (float*)d_out;

    const int* src = ei;
    const int* dst = ei + N_EDGES;

    // workspace layout (4B units)
    int*            hist    = (int*)d_ws;                         // [0, 800)
    int*            bse     = hist + 800;                         // [800, 1600)
    int*            cur     = bse + 800;                          // [1600, 2400)
    int*            row_ptr = cur + 800;                          // [2400, 102400)
    int*            deg     = row_ptr + N_NODES;                  // [102400, 202400)
    float*          dinv    = (float*)(deg + N_NODES);            // [202400, 302400)
    int*            col     = (int*)(dinv + N_NODES);             // [302400, 3502400)
    unsigned short* h1p     = (unsigned short*)(col + N_EDGES);   // [3502400, 4302400)  bf16 N*16
    unsigned*       colp    = (unsigned*)((int*)col + N_EDGES + 800000);  // [4302400, 7502400)
    unsigned short* h2p     = (unsigned short*)colp;              // aliases colp (dead after k_build)

    // build bucketed edge list
    hipMemsetAsync(hist, 0, NBUCK * sizeof(int), stream);
    k_hist0<<<(N_EDGES + 8191) / 8192, 256, 0, stream>>>(dst, hist, N_EDGES);
    k_scan0<<<1, 128, 0, stream>>>(hist, bse, cur);
    k_bucket<<<(N_EDGES + 4095) / 4096, 256, 0, stream>>>(src, dst, cur, colp, N_EDGES);
    // per-bucket counting sort -> full CSR + degrees + dinv
    k_build<<<NBUCK, 1024, 0, stream>>>(colp, bse, hist, col, row_ptr, deg, dinv);

    // h1' = bf16(dinv * (x @ W1))
    k_gemm1<<<(N_NODES + 15) / 16, 256, 0, stream>>>(x, W1, dinv, h1p, N_NODES);

    // layer 1: gather + bias + relu + pre-scale  (h2p aliases colp region; colp dead)
    k_gather1<<<((size_t)2 * N_NODES + 255) / 256, 256, 0, stream>>>(h1p, row_ptr, deg, dinv, col,
                                                                     b1, h2p, N_NODES);

    // layer 2: gather fused with final GEMM + bias
    k_gather2_out<<<(N_NODES + 127) / 128, 256, 0, stream>>>(h2p, row_ptr, deg, dinv, col, W2, b2,
                                                             out, N_NODES);
}

// Round 8
// 202.340 us; speedup vs baseline: 4.0441x; 1.0963x over previous
//
#include <hip/hip_runtime.h>
#include <hip/hip_bf16.h>

#define N_NODES 100000
#define N_EDGES 3200000
#define IN_CH 128
#define HID 16
#define OUT_CH 64
#define BSHIFT 9
#define BNODES 512              // nodes per bucket
#define NBUCK 196               // ceil(100000/512)

__device__ __forceinline__ float bf2f(unsigned short u) {
    union { unsigned v; float f; } t; t.v = ((unsigned)u) << 16; return t.f;
}
__device__ __forceinline__ unsigned short f2bf(float f) {
    union { float f; unsigned v; } t; t.f = f;
    unsigned r = t.v + 0x7FFFu + ((t.v >> 16) & 1u);   // round-to-nearest-even
    return (unsigned short)(r >> 16);
}
__device__ __forceinline__ unsigned pack2(float lo, float hi) {
    return (unsigned)f2bf(lo) | ((unsigned)f2bf(hi) << 16);
}
// accumulate 8 bf16 channels packed in a uint4 into a[0..7]
__device__ __forceinline__ void acc8(uint4 v, float* a) {
    union { unsigned u; float f; } c;
    c.u = v.x << 16;         a[0] += c.f;
    c.u = v.x & 0xffff0000u; a[1] += c.f;
    c.u = v.y << 16;         a[2] += c.f;
    c.u = v.y & 0xffff0000u; a[3] += c.f;
    c.u = v.z << 16;         a[4] += c.f;
    c.u = v.z & 0xffff0000u; a[5] += c.f;
    c.u = v.w << 16;         a[6] += c.f;
    c.u = v.w & 0xffff0000u; a[7] += c.f;
}

// ---------------- pass 0: global bucket histogram (LDS-privatized, 4x MLP) ----------------
__global__ __launch_bounds__(256) void k_hist0(const int* __restrict__ dst, int* __restrict__ hist, int e) {
    __shared__ int lh[NBUCK];
    int t = threadIdx.x;
    if (t < NBUCK) lh[t] = 0;
    __syncthreads();
    int base = blockIdx.x * 8192;
    for (int j = 0; j < 8192; j += 1024) {
        int i0 = base + j + t, i1 = i0 + 256, i2 = i0 + 512, i3 = i0 + 768;
        int d0 = (i0 < e) ? dst[i0] : -1;
        int d1 = (i1 < e) ? dst[i1] : -1;
        int d2 = (i2 < e) ? dst[i2] : -1;
        int d3 = (i3 < e) ? dst[i3] : -1;
        if (d0 >= 0) atomicAdd(&lh[d0 >> BSHIFT], 1);
        if (d1 >= 0) atomicAdd(&lh[d1 >> BSHIFT], 1);
        if (d2 >= 0) atomicAdd(&lh[d2 >> BSHIFT], 1);
        if (d3 >= 0) atomicAdd(&lh[d3 >> BSHIFT], 1);
    }
    __syncthreads();
    if (t < NBUCK && lh[t]) atomicAdd(&hist[t], lh[t]);
}

// ---------------- scan 196 bucket counts -> base + cursor ----------------
__global__ __launch_bounds__(256) void k_scan0(const int* __restrict__ hist, int* __restrict__ bse,
                                               int* __restrict__ cur) {
    __shared__ int sh[256];
    int t = threadIdx.x;
    int v = (t < NBUCK) ? hist[t] : 0;
    sh[t] = v;
    __syncthreads();
    for (int off = 1; off < 256; off <<= 1) {
        int x = (t >= off) ? sh[t - off] : 0;
        __syncthreads();
        sh[t] += x;
        __syncthreads();
    }
    if (t < NBUCK) { int ex = sh[t] - v; bse[t] = ex; cur[t] = ex; }
}

// ---------------- pass 1: scatter packed edges into bucket runs (block-coalesced) ----------------
__global__ __launch_bounds__(256) void k_bucket(const int* __restrict__ src, const int* __restrict__ dst,
                                                int* __restrict__ cur, unsigned* __restrict__ colp, int e) {
    __shared__ int lh[NBUCK];
    __shared__ int lb[NBUCK];
    int t = threadIdx.x;
    if (t < NBUCK) lh[t] = 0;
    __syncthreads();
    int base = blockIdx.x * 4096;
    int bk[16]; int rk[16]; unsigned pk[16];
#pragma unroll
    for (int j = 0; j < 16; ++j) {
        int idx = base + j * 256 + t;
        if (idx < e) {
            int d = dst[idx];
            int b = d >> BSHIFT;
            bk[j] = b;
            pk[j] = ((unsigned)(d & (BNODES - 1)) << 17) | (unsigned)src[idx];
            rk[j] = atomicAdd(&lh[b], 1);
        } else bk[j] = -1;
    }
    __syncthreads();
    if (t < NBUCK) { int c = lh[t]; lb[t] = c ? atomicAdd(&cur[t], c) : 0; }
    __syncthreads();
#pragma unroll
    for (int j = 0; j < 16; ++j) if (bk[j] >= 0) colp[lb[bk[j]] + rk[j]] = pk[j];
}

// ---------------- pass 2: per-bucket counting sort -> CSR (4x MLP) ----------------
__global__ __launch_bounds__(1024) void k_build(const unsigned* __restrict__ colp, const int* __restrict__ bse,
                                                const int* __restrict__ hist, int* __restrict__ col,
                                                int* __restrict__ row_ptr, int* __restrict__ deg,
                                                float* __restrict__ dinv) {
    __shared__ int cnt[BNODES];
    __shared__ int sc[BNODES];
    __shared__ int ex[BNODES];
    __shared__ int curl[BNODES];
    int b = blockIdx.x, t = threadIdx.x;
    if (t < BNODES) cnt[t] = 0;
    __syncthreads();
    int base = bse[b], m = hist[b];
    int i = t;
    for (; i + 3072 < m; i += 4096) {
        unsigned p0 = colp[base + i];
        unsigned p1 = colp[base + i + 1024];
        unsigned p2 = colp[base + i + 2048];
        unsigned p3 = colp[base + i + 3072];
        atomicAdd(&cnt[p0 >> 17], 1);
        atomicAdd(&cnt[p1 >> 17], 1);
        atomicAdd(&cnt[p2 >> 17], 1);
        atomicAdd(&cnt[p3 >> 17], 1);
    }
    for (; i < m; i += 1024) atomicAdd(&cnt[colp[base + i] >> 17], 1);
    __syncthreads();
    int v = 0;
    if (t < BNODES) { v = cnt[t]; sc[t] = v; }
    __syncthreads();
    for (int off = 1; off < BNODES; off <<= 1) {
        int x = 0;
        if (t < BNODES && t >= off) x = sc[t - off];
        __syncthreads();
        if (t < BNODES) sc[t] += x;
        __syncthreads();
    }
    if (t < BNODES) {
        ex[t] = sc[t] - v;
        curl[t] = 0;
        int node = b * BNODES + t;
        if (node < N_NODES) {
            row_ptr[node] = base + ex[t];
            deg[node] = v;
            dinv[node] = rsqrtf((float)v + 1.0f);
        }
    }
    __syncthreads();
    i = t;
    for (; i + 3072 < m; i += 4096) {
        unsigned p0 = colp[base + i];
        unsigned p1 = colp[base + i + 1024];
        unsigned p2 = colp[base + i + 2048];
        unsigned p3 = colp[base + i + 3072];
        int l0 = p0 >> 17, l1 = p1 >> 17, l2 = p2 >> 17, l3 = p3 >> 17;
        int q0 = atomicAdd(&curl[l0], 1);
        int q1 = atomicAdd(&curl[l1], 1);
        int q2 = atomicAdd(&curl[l2], 1);
        int q3 = atomicAdd(&curl[l3], 1);
        col[base + ex[l0] + q0] = (int)(p0 & 0x1FFFF);
        col[base + ex[l1] + q1] = (int)(p1 & 0x1FFFF);
        col[base + ex[l2] + q2] = (int)(p2 & 0x1FFFF);
        col[base + ex[l3] + q3] = (int)(p3 & 0x1FFFF);
    }
    for (; i < m; i += 1024) {
        unsigned pv = colp[base + i];
        int l = pv >> 17;
        int p = atomicAdd(&curl[l], 1);
        col[base + ex[l] + p] = (int)(pv & 0x1FFFF);
    }
}

// ---------------- h1' = bf16( dinv * (x @ W1) )  (N x 128) @ (128 x 16) ----------------
__global__ __launch_bounds__(256) void k_gemm1(const float* __restrict__ x,
                                               const float* __restrict__ W1,
                                               const float* __restrict__ dinv,
                                               unsigned short* __restrict__ h1p, int n) {
    __shared__ float Ws[IN_CH * HID];
    __shared__ float xs[16][IN_CH + 1];
    int tid = threadIdx.x;
    for (int i = tid; i < IN_CH * HID; i += 256) Ws[i] = W1[i];
    int row0 = blockIdx.x * 16;
    for (int i = tid; i < 16 * IN_CH; i += 256) {
        int r = i / IN_CH, c = i % IN_CH;
        int row = row0 + r;
        xs[r][c] = (row < n) ? x[(size_t)row * IN_CH + c] : 0.f;
    }
    __syncthreads();
    int r = tid >> 4, c = tid & 15;
    float acc = 0.f;
#pragma unroll
    for (int k = 0; k < IN_CH; ++k) acc = fmaf(xs[r][k], Ws[k * HID + c], acc);
    int row = row0 + r;
    if (row < n) h1p[(size_t)row * HID + c] = f2bf(dinv[row] * acc);
}

// ---------------- gather layer 1: 2 threads/node, 16B loads, 4x unroll ----------------
__global__ __launch_bounds__(256) void k_gather1(const unsigned short* __restrict__ h1p,
                                                 const int* __restrict__ row_ptr,
                                                 const int* __restrict__ deg,
                                                 const float* __restrict__ dinv,
                                                 const int* __restrict__ col,
                                                 const float* __restrict__ b1,
                                                 unsigned short* __restrict__ h2p, int n) {
    int t = blockIdx.x * blockDim.x + threadIdx.x;
    int i = t >> 1, q = t & 1;                 // 2 threads/node, 8 ch each
    if (i >= n) return;
    const uint4* hp = reinterpret_cast<const uint4*>(h1p);   // row i = hp[2i], hp[2i+1]
    float a[8] = {0, 0, 0, 0, 0, 0, 0, 0};
    acc8(hp[(size_t)i * 2 + q], a);            // self-loop
    int j0 = row_ptr[i], j1 = j0 + deg[i];
    int j = j0;
    for (; j + 3 < j1; j += 4) {
        int s0 = col[j], s1 = col[j + 1], s2 = col[j + 2], s3 = col[j + 3];
        uint4 v0 = hp[(size_t)s0 * 2 + q];
        uint4 v1 = hp[(size_t)s1 * 2 + q];
        uint4 v2 = hp[(size_t)s2 * 2 + q];
        uint4 v3 = hp[(size_t)s3 * 2 + q];
        acc8(v0, a); acc8(v1, a); acc8(v2, a); acc8(v3, a);
    }
    for (; j < j1; ++j) acc8(hp[(size_t)col[j] * 2 + q], a);
    float di = dinv[i];
    float4 bl = *reinterpret_cast<const float4*>(&b1[q * 8]);
    float4 bh = *reinterpret_cast<const float4*>(&b1[q * 8 + 4]);
    float o[8];
    o[0] = di * fmaxf(fmaf(di, a[0], bl.x), 0.f);
    o[1] = di * fmaxf(fmaf(di, a[1], bl.y), 0.f);
    o[2] = di * fmaxf(fmaf(di, a[2], bl.z), 0.f);
    o[3] = di * fmaxf(fmaf(di, a[3], bl.w), 0.f);
    o[4] = di * fmaxf(fmaf(di, a[4], bh.x), 0.f);
    o[5] = di * fmaxf(fmaf(di, a[5], bh.y), 0.f);
    o[6] = di * fmaxf(fmaf(di, a[6], bh.z), 0.f);
    o[7] = di * fmaxf(fmaf(di, a[7], bh.w), 0.f);
    uint4 ov;
    ov.x = pack2(o[0], o[1]);
    ov.y = pack2(o[2], o[3]);
    ov.z = pack2(o[4], o[5]);
    ov.w = pack2(o[6], o[7]);
    reinterpret_cast<uint4*>(h2p)[(size_t)i * 2 + q] = ov;
}

// ---------------- gather layer 2 (128 nodes/block) fused with (N x 16)@(16 x 64) + b2 ----------------
__global__ __launch_bounds__(256) void k_gather2_out(const unsigned short* __restrict__ h2p,
                                                     const int* __restrict__ row_ptr,
                                                     const int* __restrict__ deg,
                                                     const float* __restrict__ dinv,
                                                     const int* __restrict__ col,
                                                     const float* __restrict__ W2,
                                                     const float* __restrict__ b2,
                                                     float* __restrict__ out, int n) {
    __shared__ float Ws[HID * OUT_CH];    // 4 KB
    __shared__ float as[128][HID + 1];    // 8.7 KB
    int t = threadIdx.x;
    for (int i = t; i < HID * OUT_CH; i += 256) Ws[i] = W2[i];
    int i0 = blockIdx.x * 128;
    int nl = t >> 1, q = t & 1;
    int i = i0 + nl;
    const uint4* hp = reinterpret_cast<const uint4*>(h2p);
    if (i < n) {
        float a[8] = {0, 0, 0, 0, 0, 0, 0, 0};
        acc8(hp[(size_t)i * 2 + q], a);    // self
        int j0 = row_ptr[i], j1 = j0 + deg[i];
        int j = j0;
        for (; j + 3 < j1; j += 4) {
            int s0 = col[j], s1 = col[j + 1], s2 = col[j + 2], s3 = col[j + 3];
            uint4 v0 = hp[(size_t)s0 * 2 + q];
            uint4 v1 = hp[(size_t)s1 * 2 + q];
            uint4 v2 = hp[(size_t)s2 * 2 + q];
            uint4 v3 = hp[(size_t)s3 * 2 + q];
            acc8(v0, a); acc8(v1, a); acc8(v2, a); acc8(v3, a);
        }
        for (; j < j1; ++j) acc8(hp[(size_t)col[j] * 2 + q], a);
        float di = dinv[i];
#pragma unroll
        for (int k = 0; k < 8; ++k) as[nl][q * 8 + k] = di * a[k];
    } else {
#pragma unroll
        for (int k = 0; k < 8; ++k) as[nl][q * 8 + k] = 0.f;
    }
    __syncthreads();
    // epilogue: node nl, cols g*32 .. g*32+31
    int g = q;
    float r[32];
#pragma unroll
    for (int c = 0; c < 32; ++c) r[c] = b2[g * 32 + c];
#pragma unroll
    for (int k = 0; k < HID; ++k) {
        float a = as[nl][k];
#pragma unroll
        for (int c = 0; c < 32; ++c) r[c] = fmaf(a, Ws[k * OUT_CH + g * 32 + c], r[c]);
    }
    if (i < n) {
        float* op = &out[(size_t)i * OUT_CH + g * 32];
#pragma unroll
        for (int c = 0; c < 32; c += 4)
            *reinterpret_cast<float4*>(&op[c]) = make_float4(r[c], r[c + 1], r[c + 2], r[c + 3]);
    }
}

extern "C" void kernel_launch(void* const* d_in, const int* in_sizes, int n_in,
                              void* d_out, int out_size, void* d_ws, size_t ws_size,
                              hipStream_t stream) {
    const float* x  = (const float*)d_in[0];
    const int*   ei = (const int*)d_in[1];
    const float* W1 = (const float*)d_in[2];
    const float* b1 = (const float*)d_in[3];
    const float* W2 = (const float*)d_in[4];
    const float* b2 = (const float*)d_in[5];
    float* out = (float*)d_out;

    const int* src = ei;
    const int* dst = ei + N_EDGES;

    // workspace layout (4B units)
    int*            hist    = (int*)d_ws;                         // [0, 800)
    int*            bse     = hist + 800;                         // [800, 1600)
    int*            cur     = bse + 800;                          // [1600, 2400)
    int*            row_ptr = cur + 800;                          // [2400, 102400)
    int*            deg     = row_ptr + N_NODES;                  // [102400, 202400)
    float*          dinv    = (float*)(deg + N_NODES);            // [202400, 302400)
    int*            col     = (int*)(dinv + N_NODES);             // [302400, 3502400)
    unsigned short* h1p     = (unsigned short*)(col + N_EDGES);   // [3502400, 4302400)  bf16 N*16
    unsigned*       colp    = (unsigned*)((int*)col + N_EDGES + 800000);  // [4302400, 7502400)
    unsigned short* h2p     = (unsigned short*)colp;              // aliases colp (dead after k_build)

    // build bucketed edge list
    hipMemsetAsync(hist, 0, NBUCK * sizeof(int), stream);
    k_hist0<<<(N_EDGES + 8191) / 8192, 256, 0, stream>>>(dst, hist, N_EDGES);
    k_scan0<<<1, 256, 0, stream>>>(hist, bse, cur);
    k_bucket<<<(N_EDGES + 4095) / 4096, 256, 0, stream>>>(src, dst, cur, colp, N_EDGES);
    // per-bucket counting sort -> full CSR + degrees + dinv
    k_build<<<NBUCK, 1024, 0, stream>>>(colp, bse, hist, col, row_ptr, deg, dinv);

    // h1' = bf16(dinv * (x @ W1))
    k_gemm1<<<(N_NODES + 15) / 16, 256, 0, stream>>>(x, W1, dinv, h1p, N_NODES);

    // layer 1: gather + bias + relu + pre-scale  (h2p aliases colp region; colp dead)
    k_gather1<<<((size_t)2 * N_NODES + 255) / 256, 256, 0, stream>>>(h1p, row_ptr, deg, dinv, col,
                                                                     b1, h2p, N_NODES);

    // layer 2: gather fused with final GEMM + bias
    k_gather2_out<<<(N_NODES + 127) / 128, 256, 0, stream>>>(h2p, row_ptr, deg, dinv, col, W2, b2,
                                                             out, N_NODES);
}

// Round 10
// 163.943 us; speedup vs baseline: 4.9913x; 1.2342x over previous
//
#include <hip/hip_runtime.h>
#include <hip/hip_bf16.h>

#define N_NODES 100000
#define N_EDGES 3200000
#define IN_CH 128
#define HID 16
#define OUT_CH 64
#define BSHIFT 9
#define BNODES 512              // nodes per bucket
#define NBUCK 196               // ceil(100000/512)
#define BCAP 18000              // per-bucket colp capacity (mean 16384 + ~12 sigma)

__device__ __forceinline__ unsigned short f2bf(float f) {
    union { float f; unsigned v; } t; t.f = f;
    unsigned r = t.v + 0x7FFFu + ((t.v >> 16) & 1u);   // round-to-nearest-even
    return (unsigned short)(r >> 16);
}
__device__ __forceinline__ unsigned pack2(float lo, float hi) {
    return (unsigned)f2bf(lo) | ((unsigned)f2bf(hi) << 16);
}
// accumulate 8 bf16 channels packed in a uint4 into a[0..7]
__device__ __forceinline__ void acc8(uint4 v, float* a) {
    union { unsigned u; float f; } c;
    c.u = v.x << 16;         a[0] += c.f;
    c.u = v.x & 0xffff0000u; a[1] += c.f;
    c.u = v.y << 16;         a[2] += c.f;
    c.u = v.y & 0xffff0000u; a[3] += c.f;
    c.u = v.z << 16;         a[4] += c.f;
    c.u = v.z & 0xffff0000u; a[5] += c.f;
    c.u = v.w << 16;         a[6] += c.f;
    c.u = v.w & 0xffff0000u; a[7] += c.f;
}

// ---------------- init per-bucket cursors to fixed-capacity bases ----------------
__global__ void k_init_cur(int* __restrict__ cur) {
    int t = threadIdx.x;
    if (t < NBUCK) cur[t] = t * BCAP;
}

// ---------------- pass 1: scatter packed edges into bucket runs (single pass, no hist) ----------------
__global__ __launch_bounds__(256) void k_bucket(const int* __restrict__ src, const int* __restrict__ dst,
                                                int* __restrict__ cur, unsigned* __restrict__ colp, int e) {
    __shared__ int lh[NBUCK];
    __shared__ int lb[NBUCK];
    int t = threadIdx.x;
    if (t < NBUCK) lh[t] = 0;
    __syncthreads();
    int base = blockIdx.x * 4096;
    int bk[16]; int rk[16]; unsigned pk[16];
#pragma unroll
    for (int j = 0; j < 16; ++j) {
        int idx = base + j * 256 + t;
        if (idx < e) {
            int d = dst[idx];
            int b = d >> BSHIFT;
            bk[j] = b;
            pk[j] = ((unsigned)(d & (BNODES - 1)) << 17) | (unsigned)src[idx];
            rk[j] = atomicAdd(&lh[b], 1);
        } else bk[j] = -1;
    }
    __syncthreads();
    if (t < NBUCK) { int c = lh[t]; lb[t] = c ? atomicAdd(&cur[t], c) : 0; }
    __syncthreads();
#pragma unroll
    for (int j = 0; j < 16; ++j) if (bk[j] >= 0) colp[lb[bk[j]] + rk[j]] = pk[j];
}

// ---------------- pass 2: per-bucket counting sort -> CSR (4x MLP) ----------------
__global__ __launch_bounds__(1024) void k_build(const unsigned* __restrict__ colp, const int* __restrict__ cur,
                                                int* __restrict__ col, int* __restrict__ row_ptr,
                                                int* __restrict__ deg, float* __restrict__ dinv) {
    __shared__ int cnt[BNODES];
    __shared__ int sc[BNODES];
    __shared__ int ex[BNODES];
    __shared__ int curl[BNODES];
    int b = blockIdx.x, t = threadIdx.x;
    if (t < BNODES) cnt[t] = 0;
    __syncthreads();
    int base = b * BCAP;
    int m = cur[b] - base;
    int i = t;
    for (; i + 3072 < m; i += 4096) {
        unsigned p0 = colp[base + i];
        unsigned p1 = colp[base + i + 1024];
        unsigned p2 = colp[base + i + 2048];
        unsigned p3 = colp[base + i + 3072];
        atomicAdd(&cnt[p0 >> 17], 1);
        atomicAdd(&cnt[p1 >> 17], 1);
        atomicAdd(&cnt[p2 >> 17], 1);
        atomicAdd(&cnt[p3 >> 17], 1);
    }
    for (; i < m; i += 1024) atomicAdd(&cnt[colp[base + i] >> 17], 1);
    __syncthreads();
    int v = 0;
    if (t < BNODES) { v = cnt[t]; sc[t] = v; }
    __syncthreads();
    for (int off = 1; off < BNODES; off <<= 1) {
        int x = 0;
        if (t < BNODES && t >= off) x = sc[t - off];
        __syncthreads();
        if (t < BNODES) sc[t] += x;
        __syncthreads();
    }
    if (t < BNODES) {
        ex[t] = sc[t] - v;
        curl[t] = 0;
        int node = b * BNODES + t;
        if (node < N_NODES) {
            row_ptr[node] = base + ex[t];
            deg[node] = v;
            dinv[node] = rsqrtf((float)v + 1.0f);
        }
    }
    __syncthreads();
    i = t;
    for (; i + 3072 < m; i += 4096) {
        unsigned p0 = colp[base + i];
        unsigned p1 = colp[base + i + 1024];
        unsigned p2 = colp[base + i + 2048];
        unsigned p3 = colp[base + i + 3072];
        int l0 = p0 >> 17, l1 = p1 >> 17, l2 = p2 >> 17, l3 = p3 >> 17;
        int q0 = atomicAdd(&curl[l0], 1);
        int q1 = atomicAdd(&curl[l1], 1);
        int q2 = atomicAdd(&curl[l2], 1);
        int q3 = atomicAdd(&curl[l3], 1);
        col[base + ex[l0] + q0] = (int)(p0 & 0x1FFFF);
        col[base + ex[l1] + q1] = (int)(p1 & 0x1FFFF);
        col[base + ex[l2] + q2] = (int)(p2 & 0x1FFFF);
        col[base + ex[l3] + q3] = (int)(p3 & 0x1FFFF);
    }
    for (; i < m; i += 1024) {
        unsigned pv = colp[base + i];
        int l = pv >> 17;
        int p = atomicAdd(&curl[l], 1);
        col[base + ex[l] + p] = (int)(pv & 0x1FFFF);
    }
}

// ---------------- h1' = bf16( dinv * (x @ W1) )  (N x 128) @ (128 x 16) ----------------
__global__ __launch_bounds__(256) void k_gemm1(const float* __restrict__ x,
                                               const float* __restrict__ W1,
                                               const float* __restrict__ dinv,
                                               unsigned short* __restrict__ h1p, int n) {
    __shared__ float Ws[IN_CH * HID];
    __shared__ float xs[16][IN_CH + 1];
    int tid = threadIdx.x;
    for (int i = tid; i < IN_CH * HID; i += 256) Ws[i] = W1[i];
    int row0 = blockIdx.x * 16;
    for (int i = tid; i < 16 * IN_CH; i += 256) {
        int r = i / IN_CH, c = i % IN_CH;
        int row = row0 + r;
        xs[r][c] = (row < n) ? x[(size_t)row * IN_CH + c] : 0.f;
    }
    __syncthreads();
    int r = tid >> 4, c = tid & 15;
    float acc = 0.f;
#pragma unroll
    for (int k = 0; k < IN_CH; ++k) acc = fmaf(xs[r][k], Ws[k * HID + c], acc);
    int row = row0 + r;
    if (row < n) h1p[(size_t)row * HID + c] = f2bf(dinv[row] * acc);
}

// ---------------- gather layer 1: 4 threads/node (q=ch-half, p=edge-parity), shfl combine ----------------
__global__ __launch_bounds__(256) void k_gather1(const unsigned short* __restrict__ h1p,
                                                 const int* __restrict__ row_ptr,
                                                 const int* __restrict__ deg,
                                                 const float* __restrict__ dinv,
                                                 const int* __restrict__ col,
                                                 const float* __restrict__ b1,
                                                 unsigned short* __restrict__ h2p, int n) {
    int t = blockIdx.x * blockDim.x + threadIdx.x;
    int i = t >> 2;
    if (i >= n) return;
    int q = t & 1, p = (t >> 1) & 1;
    const uint4* hp = reinterpret_cast<const uint4*>(h1p);
    float a[8] = {0, 0, 0, 0, 0, 0, 0, 0};
    int j0 = row_ptr[i], j1 = j0 + deg[i];
    int j = j0 + p;
    for (; j + 6 < j1; j += 8) {
        int s0 = col[j], s1 = col[j + 2], s2 = col[j + 4], s3 = col[j + 6];
        uint4 v0 = hp[(size_t)s0 * 2 + q];
        uint4 v1 = hp[(size_t)s1 * 2 + q];
        uint4 v2 = hp[(size_t)s2 * 2 + q];
        uint4 v3 = hp[(size_t)s3 * 2 + q];
        acc8(v0, a); acc8(v1, a); acc8(v2, a); acc8(v3, a);
    }
    for (; j < j1; j += 2) acc8(hp[(size_t)col[j] * 2 + q], a);
    // combine edge-parity partners (lane^2 is same node, same q)
#pragma unroll
    for (int k = 0; k < 8; ++k) a[k] += __shfl_xor(a[k], 2);
    if (p == 0) {
        acc8(hp[(size_t)i * 2 + q], a);   // self-loop
        float di = dinv[i];
        float4 bl = *reinterpret_cast<const float4*>(&b1[q * 8]);
        float4 bh = *reinterpret_cast<const float4*>(&b1[q * 8 + 4]);
        float o[8];
        o[0] = di * fmaxf(fmaf(di, a[0], bl.x), 0.f);
        o[1] = di * fmaxf(fmaf(di, a[1], bl.y), 0.f);
        o[2] = di * fmaxf(fmaf(di, a[2], bl.z), 0.f);
        o[3] = di * fmaxf(fmaf(di, a[3], bl.w), 0.f);
        o[4] = di * fmaxf(fmaf(di, a[4], bh.x), 0.f);
        o[5] = di * fmaxf(fmaf(di, a[5], bh.y), 0.f);
        o[6] = di * fmaxf(fmaf(di, a[6], bh.z), 0.f);
        o[7] = di * fmaxf(fmaf(di, a[7], bh.w), 0.f);
        uint4 ov;
        ov.x = pack2(o[0], o[1]);
        ov.y = pack2(o[2], o[3]);
        ov.z = pack2(o[4], o[5]);
        ov.w = pack2(o[6], o[7]);
        reinterpret_cast<uint4*>(h2p)[(size_t)i * 2 + q] = ov;
    }
}

// ---------------- gather layer 2: 4 threads/node + fused (N x 16)@(16 x 64) + b2 ----------------
__global__ __launch_bounds__(256) void k_gather2_out(const unsigned short* __restrict__ h2p,
                                                     const int* __restrict__ row_ptr,
                                                     const int* __restrict__ deg,
                                                     const float* __restrict__ dinv,
                                                     const int* __restrict__ col,
                                                     const float* __restrict__ W2,
                                                     const float* __restrict__ b2,
                                                     float* __restrict__ out, int n) {
    __shared__ float Ws[HID * OUT_CH];    // 4 KB
    __shared__ float as[64][HID + 1];     // 4.4 KB
    int t = threadIdx.x;
    for (int i = t; i < HID * OUT_CH; i += 256) Ws[i] = W2[i];
    int nl = t >> 2;                       // 64 nodes/block
    int i = blockIdx.x * 64 + nl;
    int q = t & 1, p = (t >> 1) & 1;
    const uint4* hp = reinterpret_cast<const uint4*>(h2p);
    if (i < n) {
        float a[8] = {0, 0, 0, 0, 0, 0, 0, 0};
        int j0 = row_ptr[i], j1 = j0 + deg[i];
        int j = j0 + p;
        for (; j + 6 < j1; j += 8) {
            int s0 = col[j], s1 = col[j + 2], s2 = col[j + 4], s3 = col[j + 6];
            uint4 v0 = hp[(size_t)s0 * 2 + q];
            uint4 v1 = hp[(size_t)s1 * 2 + q];
            uint4 v2 = hp[(size_t)s2 * 2 + q];
            uint4 v3 = hp[(size_t)s3 * 2 + q];
            acc8(v0, a); acc8(v1, a); acc8(v2, a); acc8(v3, a);
        }
        for (; j < j1; j += 2) acc8(hp[(size_t)col[j] * 2 + q], a);
#pragma unroll
        for (int k = 0; k < 8; ++k) a[k] += __shfl_xor(a[k], 2);
        if (p == 0) {
            acc8(hp[(size_t)i * 2 + q], a);   // self
            float di = dinv[i];
#pragma unroll
            for (int k = 0; k < 8; ++k) as[nl][q * 8 + k] = di * a[k];
        }
    } else if (p == 0) {
#pragma unroll
        for (int k = 0; k < 8; ++k) as[nl][q * 8 + k] = 0.f;
    }
    __syncthreads();
    // epilogue: node nl, cols g*16 .. g*16+15
    int g = t & 3;
    float r[16];
#pragma unroll
    for (int c = 0; c < 16; ++c) r[c] = b2[g * 16 + c];
#pragma unroll
    for (int k = 0; k < HID; ++k) {
        float a = as[nl][k];
#pragma unroll
        for (int c = 0; c < 16; ++c) r[c] = fmaf(a, Ws[k * OUT_CH + g * 16 + c], r[c]);
    }
    if (i < n) {
        float* op = &out[(size_t)i * OUT_CH + g * 16];
#pragma unroll
        for (int c = 0; c < 16; c += 4)
            *reinterpret_cast<float4*>(&op[c]) = make_float4(r[c], r[c + 1], r[c + 2], r[c + 3]);
    }
}

extern "C" void kernel_launch(void* const* d_in, const int* in_sizes, int n_in,
                              void* d_out, int out_size, void* d_ws, size_t ws_size,
                              hipStream_t stream) {
    const float* x  = (const float*)d_in[0];
    const int*   ei = (const int*)d_in[1];
    const float* W1 = (const float*)d_in[2];
    const float* b1 = (const float*)d_in[3];
    const float* W2 = (const float*)d_in[4];
    const float* b2 = (const float*)d_in[5];
    float* out = (float*)d_out;

    const int* src = ei;
    const int* dst = ei + N_EDGES;

    // workspace layout (4B units)
    int*            cur     = (int*)d_ws;                          // [0, 256)
    int*            row_ptr = cur + 256;                           // [256, 100256)
    int*            deg     = row_ptr + N_NODES;                   // [100256, 200256)
    float*          dinv    = (float*)(deg + N_NODES);             // [200256, 300256)
    int*            col     = (int*)(dinv + N_NODES);              // [300256, 3828256)  196*18000
    unsigned short* h1p     = (unsigned short*)(col + NBUCK * BCAP);  // [3828256, 4628256) bf16 N*16 = 800000 words
    unsigned*       colp    = (unsigned*)((int*)h1p + 800000);     // [4628256, 8156256)  196*18000
    unsigned short* h2p     = (unsigned short*)colp;               // aliases colp (dead after k_build)

    // single-pass bucketed edge list (fixed-capacity runs; cur pre-set to b*BCAP)
    k_init_cur<<<1, 256, 0, stream>>>(cur);
    k_bucket<<<(N_EDGES + 4095) / 4096, 256, 0, stream>>>(src, dst, cur, colp, N_EDGES);
    // per-bucket counting sort -> full CSR + degrees + dinv
    k_build<<<NBUCK, 1024, 0, stream>>>(colp, cur, col, row_ptr, deg, dinv);

    // h1' = bf16(dinv * (x @ W1))
    k_gemm1<<<(N_NODES + 15) / 16, 256, 0, stream>>>(x, W1, dinv, h1p, N_NODES);

    // layer 1: gather + bias + relu + pre-scale  (h2p aliases colp region; colp dead after k_build)
    k_gather1<<<((size_t)4 * N_NODES + 255) / 256, 256, 0, stream>>>(h1p, row_ptr, deg, dinv, col,
                                                                     b1, h2p, N_NODES);

    // layer 2: gather fused with final GEMM + bias
    k_gather2_out<<<(N_NODES + 63) / 64, 256, 0, stream>>>(h2p, row_ptr, deg, dinv, col, W2, b2,
                                                           out, N_NODES);
}